// Round 1
// baseline (684.372 us; speedup 1.0000x reference)
//
#include <hip/hip_runtime.h>

// MultiHeadSelfAttention2D: B=8, C=128, H=W=64, N=4096, heads=4, hd=32
// Pipeline: prep (transpose x -> tokens bf16, weights -> bf16)
//           proj3 (QKV via MFMA; V written transposed)
//           attn  (flash attention, 1 wave = 16 q rows, KVBLK=32)
//           projo (output projection, transposed store)

using f32x4  = __attribute__((ext_vector_type(4))) float;
using bf16x8 = __attribute__((ext_vector_type(8))) short;  // 8 bf16 in 4 VGPRs
using s16x4  = __attribute__((ext_vector_type(4))) short;

#define QSCALE 0.17677669529663687f  // 1/sqrt(32), folded into Wq/bq
#define LOG2E  1.4426950408889634f

static __device__ __forceinline__ unsigned short f2bf(float f) {
    union { float f; unsigned int u; } v; v.f = f;
    unsigned int r = v.u + 0x7FFFu + ((v.u >> 16) & 1u);  // RNE
    return (unsigned short)(r >> 16);
}

static __device__ __forceinline__ f32x4 mfma16(bf16x8 a, bf16x8 b, f32x4 c) {
    return __builtin_amdgcn_mfma_f32_16x16x32_bf16(a, b, c, 0, 0, 0);
}

// ---------------------------------------------------------------------------
// prep: x (B,128,4096) f32 -> t_bf (B,4096,128) bf16 ; weights f32 -> bf16
// blocks 0..1023: transpose tiles (64c x 64n). blocks 1024..1027: weights.
__global__ __launch_bounds__(256) void k_prep(
    const float* __restrict__ x,
    const float* __restrict__ Wq, const float* __restrict__ Wk,
    const float* __restrict__ Wv, const float* __restrict__ Wo,
    unsigned short* __restrict__ t_bf, unsigned short* __restrict__ Wb)
{
    const int bx = blockIdx.x;
    const int tid = threadIdx.x;
    if (bx >= 1024) {
        const int m = bx - 1024;
        const float* W = (m == 0) ? Wq : (m == 1) ? Wk : (m == 2) ? Wv : Wo;
        const float s = (m == 0) ? QSCALE : 1.0f;
        for (int idx = tid; idx < 16384; idx += 256)
            Wb[m * 16384 + idx] = f2bf(W[idx] * s);
        return;
    }
    __shared__ float tl[64][65];  // +1 pad: conflict-free transpose
    const int b  = bx >> 7;
    const int c0 = ((bx >> 6) & 1) * 64;
    const int n0 = (bx & 63) * 64;
    for (int idx = tid; idx < 4096; idx += 256) {
        const int ci = idx >> 6, nj = idx & 63;
        tl[ci][nj] = x[((size_t)(b * 128 + c0 + ci)) * 4096 + n0 + nj];
    }
    __syncthreads();
    for (int idx = tid; idx < 4096; idx += 256) {
        const int nj = idx >> 6, ci = idx & 63;
        t_bf[((size_t)(b * 4096 + n0 + nj)) * 128 + c0 + ci] = f2bf(tl[ci][nj]);
    }
}

// ---------------------------------------------------------------------------
// proj3: Q/K/V = t @ W^T + b.   grid (512, 3): 64 tokens/block, blockIdx.y=mat.
// Q,K stored (bh, n, 32) bf16 (Q pre-scaled). V stored transposed (bh, 32, n).
// mat<2: D = t . W^T (A=t rows, B=W rows).  mat==2: operands swapped -> D=V^T.
__global__ __launch_bounds__(256) void k_proj3(
    const unsigned short* __restrict__ t_bf, const unsigned short* __restrict__ Wb,
    const float* __restrict__ bq, const float* __restrict__ bk, const float* __restrict__ bv,
    unsigned short* __restrict__ Qb, unsigned short* __restrict__ Kb,
    unsigned short* __restrict__ Vt)
{
    const int mat  = blockIdx.y;
    const int widx = threadIdx.x >> 6;
    const int lane = threadIdx.x & 63;
    const int g = lane >> 4, l15 = lane & 15;
    const int row0 = blockIdx.x * 64 + widx * 16;
    const int gt_row = row0 + l15;
    const unsigned short* Wm = Wb + mat * 16384;
    const float* bias = (mat == 0) ? bq : (mat == 1) ? bk : bv;

    bf16x8 tf[4];
    #pragma unroll
    for (int kc = 0; kc < 4; ++kc)
        tf[kc] = *(const bf16x8*)(t_bf + (size_t)gt_row * 128 + kc * 32 + g * 8);

    #pragma unroll
    for (int ot = 0; ot < 8; ++ot) {
        f32x4 acc;
        if (mat < 2) {
            float bb = bias[ot * 16 + l15];
            if (mat == 0) bb *= QSCALE;
            acc[0] = bb; acc[1] = bb; acc[2] = bb; acc[3] = bb;
        } else {
            #pragma unroll
            for (int r = 0; r < 4; ++r) acc[r] = bias[ot * 16 + 4 * g + r];
        }
        #pragma unroll
        for (int kc = 0; kc < 4; ++kc) {
            bf16x8 wf = *(const bf16x8*)(Wm + (size_t)(ot * 16 + l15) * 128 + kc * 32 + g * 8);
            acc = (mat == 2) ? mfma16(wf, tf[kc], acc) : mfma16(tf[kc], wf, acc);
        }
        if (mat < 2) {
            unsigned short* dst = (mat == 0) ? Qb : Kb;
            const int o = ot * 16 + l15, h = o >> 5, d = o & 31;
            #pragma unroll
            for (int r = 0; r < 4; ++r) {
                const int gt = row0 + 4 * g + r;
                const int b = gt >> 12, n = gt & 4095;
                dst[(((size_t)(b * 4 + h)) * 4096 + n) * 32 + d] = f2bf(acc[r]);
            }
        } else {
            const int b = gt_row >> 12, n = gt_row & 4095;
            #pragma unroll
            for (int r = 0; r < 4; ++r) {
                const int o = ot * 16 + 4 * g + r, h = o >> 5, d = o & 31;
                Vt[(((size_t)(b * 4 + h)) * 32 + d) * 4096 + n] = f2bf(acc[r]);
            }
        }
    }
}

// ---------------------------------------------------------------------------
// attn: flash attention. 1 wave = 16 q rows of one (b,h); KVBLK=32.
// Swapped QK^T: mfma(K,Q) -> S^T tile, lane holds S[q=l15][kv0+16h'+4g+r].
// P packed in-register into PV A-frag; V B-frag loaded with identical slot map
// (k = 16*(j>>2) + 4g + (j&3)) -> layout-permutation cancels.
__global__ __launch_bounds__(256) void k_attn(
    const unsigned short* __restrict__ Qb, const unsigned short* __restrict__ Kb,
    const unsigned short* __restrict__ Vt, unsigned short* __restrict__ Ob)
{
    const int wg = blockIdx.x * 4 + (threadIdx.x >> 6);
    const int bh = wg >> 8, q0 = (wg & 255) * 16;
    const int lane = threadIdx.x & 63, g = lane >> 4, l15 = lane & 15;

    const bf16x8 qf = *(const bf16x8*)(Qb + ((size_t)bh * 4096 + q0 + l15) * 32 + g * 8);
    const unsigned short* Kbh = Kb + (size_t)bh * 131072;
    const unsigned short* Vbh = Vt + (size_t)bh * 131072;

    f32x4 acc0 = {0.f, 0.f, 0.f, 0.f}, acc1 = {0.f, 0.f, 0.f, 0.f};
    float m_run = -1e30f, l_run = 0.f;
    const f32x4 z = {0.f, 0.f, 0.f, 0.f};

    for (int it = 0; it < 128; ++it) {
        const int kv0 = it * 32;
        bf16x8 kf0 = *(const bf16x8*)(Kbh + (size_t)(kv0 + l15) * 32 + g * 8);
        bf16x8 kf1 = *(const bf16x8*)(Kbh + (size_t)(kv0 + 16 + l15) * 32 + g * 8);
        f32x4 s0 = mfma16(kf0, qf, z);  // S[q=l15][kv0+4g+r]
        f32x4 s1 = mfma16(kf1, qf, z);  // S[q=l15][kv0+16+4g+r]

        float tm = fmaxf(fmaxf(fmaxf(s0[0], s0[1]), fmaxf(s0[2], s0[3])),
                         fmaxf(fmaxf(s1[0], s1[1]), fmaxf(s1[2], s1[3])));
        tm = fmaxf(tm, __shfl_xor(tm, 16));
        tm = fmaxf(tm, __shfl_xor(tm, 32));
        const float m_new = fmaxf(m_run, tm);
        const float sc = exp2f((m_run - m_new) * LOG2E);

        float p[8];
        #pragma unroll
        for (int i = 0; i < 4; ++i) p[i]     = exp2f((s0[i] - m_new) * LOG2E);
        #pragma unroll
        for (int i = 0; i < 4; ++i) p[4 + i] = exp2f((s1[i] - m_new) * LOG2E);

        float ps = ((p[0] + p[1]) + (p[2] + p[3])) + ((p[4] + p[5]) + (p[6] + p[7]));
        ps += __shfl_xor(ps, 16);
        ps += __shfl_xor(ps, 32);
        l_run = l_run * sc + ps;
        m_run = m_new;

        // rescale acc: acc row = q0+4g+r, its scale lives at lane l15==4g+r
        #pragma unroll
        for (int r = 0; r < 4; ++r) {
            const float scf = __shfl(sc, g * 4 + r);
            acc0[r] *= scf; acc1[r] *= scf;
        }

        // PV A-frag: slot (g,j) -> kv = 16*(j>>2) + 4g + (j&3)  (what we hold)
        bf16x8 pa;
        #pragma unroll
        for (int j = 0; j < 4; ++j) pa[j] = (short)f2bf(p[j]);
        #pragma unroll
        for (int j = 0; j < 4; ++j) pa[4 + j] = (short)f2bf(p[4 + j]);

        // V B-frag with the SAME slot map; Vt is (d, n) so loads are contiguous
        const unsigned short* vr0 = Vbh + (size_t)l15 * 4096 + kv0 + 4 * g;
        const unsigned short* vr1 = vr0 + 16 * 4096;
        s16x4 v00 = *(const s16x4*)(vr0);
        s16x4 v01 = *(const s16x4*)(vr0 + 16);
        s16x4 v10 = *(const s16x4*)(vr1);
        s16x4 v11 = *(const s16x4*)(vr1 + 16);
        bf16x8 vf0, vf1;
        #pragma unroll
        for (int j = 0; j < 4; ++j) {
            vf0[j] = v00[j]; vf0[4 + j] = v01[j];
            vf1[j] = v10[j]; vf1[4 + j] = v11[j];
        }
        acc0 = mfma16(pa, vf0, acc0);  // O cols 0..15
        acc1 = mfma16(pa, vf1, acc1);  // O cols 16..31
    }

    const int b = bh >> 2, h = bh & 3;
    #pragma unroll
    for (int r = 0; r < 4; ++r) {
        const float lr = __shfl(l_run, g * 4 + r);
        const float rinv = 1.0f / lr;
        const size_t base = ((size_t)b * 4096 + q0 + 4 * g + r) * 128 + h * 32;
        Ob[base + l15]      = f2bf(acc0[r] * rinv);
        Ob[base + 16 + l15] = f2bf(acc1[r] * rinv);
    }
}

// ---------------------------------------------------------------------------
// projo: out(b,c,n) = (O @ Wo^T + bo)^T via swapped MFMA (A=Wo rows, B=O rows)
__global__ __launch_bounds__(256) void k_projo(
    const unsigned short* __restrict__ Ob, const unsigned short* __restrict__ Wob,
    const float* __restrict__ bo, float* __restrict__ out)
{
    const int widx = threadIdx.x >> 6;
    const int lane = threadIdx.x & 63, g = lane >> 4, l15 = lane & 15;
    const int gt = blockIdx.x * 64 + widx * 16 + l15;  // token (col of D)
    const int b = gt >> 12, n = gt & 4095;

    bf16x8 of[4];
    #pragma unroll
    for (int kc = 0; kc < 4; ++kc)
        of[kc] = *(const bf16x8*)(Ob + (size_t)gt * 128 + kc * 32 + g * 8);

    #pragma unroll
    for (int ot = 0; ot < 8; ++ot) {
        f32x4 acc;
        #pragma unroll
        for (int r = 0; r < 4; ++r) acc[r] = bo[ot * 16 + 4 * g + r];
        #pragma unroll
        for (int kc = 0; kc < 4; ++kc) {
            bf16x8 wf = *(const bf16x8*)(Wob + (size_t)(ot * 16 + l15) * 128 + kc * 32 + g * 8);
            acc = mfma16(wf, of[kc], acc);
        }
        #pragma unroll
        for (int r = 0; r < 4; ++r)
            out[((size_t)b * 128 + ot * 16 + 4 * g + r) * 4096 + n] = acc[r];
    }
}

// ---------------------------------------------------------------------------
extern "C" void kernel_launch(void* const* d_in, const int* in_sizes, int n_in,
                              void* d_out, int out_size, void* d_ws, size_t ws_size,
                              hipStream_t stream)
{
    const float* x  = (const float*)d_in[0];
    const float* Wq = (const float*)d_in[1];
    const float* bq = (const float*)d_in[2];
    const float* Wk = (const float*)d_in[3];
    const float* bk = (const float*)d_in[4];
    const float* Wv = (const float*)d_in[5];
    const float* bv = (const float*)d_in[6];
    const float* Wo = (const float*)d_in[7];
    const float* bo = (const float*)d_in[8];
    float* out = (float*)d_out;

    char* ws = (char*)d_ws;
    unsigned short* t_bf = (unsigned short*)(ws);             //  8,388,608 B
    unsigned short* Wb   = (unsigned short*)(ws +  8388608);  //    131,072 B
    unsigned short* Qb   = (unsigned short*)(ws +  8519680);  //  8,388,608 B
    unsigned short* Kb   = (unsigned short*)(ws + 16908288);  //  8,388,608 B
    unsigned short* Vt   = (unsigned short*)(ws + 25296896);  //  8,388,608 B
    unsigned short* Ob   = (unsigned short*)(ws + 33685504);  //  8,388,608 B -> 42.1 MB total

    k_prep <<<dim3(1028),     dim3(256), 0, stream>>>(x, Wq, Wk, Wv, Wo, t_bf, Wb);
    k_proj3<<<dim3(512, 3),   dim3(256), 0, stream>>>(t_bf, Wb, bq, bk, bv, Qb, Kb, Vt);
    k_attn <<<dim3(2048),     dim3(256), 0, stream>>>(Qb, Kb, Vt, Ob);
    k_projo<<<dim3(512),      dim3(256), 0, stream>>>(Ob, Wb + 3 * 16384, bo, out);
}

// Round 2
// 412.715 us; speedup vs baseline: 1.6582x; 1.6582x over previous
//
#include <hip/hip_runtime.h>

// MultiHeadSelfAttention2D: B=8, C=128, H=W=64, N=4096, heads=4, hd=32
// Pipeline: prep (transpose x -> tokens bf16, weights -> bf16)
//           proj3 (QKV via MFMA; V written transposed)
//           attn  (flash attention, 1 wave = 32 q rows, KVBLK=32,
//                  defer-max + ones-column denominator + cvt_pk + prefetch)
//           projo (output projection, transposed store)

using f32x4  = __attribute__((ext_vector_type(4))) float;
using bf16x8 = __attribute__((ext_vector_type(8))) short;  // 8 bf16 in 4 VGPRs
using s16x4  = __attribute__((ext_vector_type(4))) short;

#define QSCALE 0.17677669529663687f  // 1/sqrt(32), folded into Wq/bq
#define LOG2E  1.4426950408889634f
#define THR    8.0f                  // defer-max threshold (natural-log units)

static __device__ __forceinline__ unsigned short f2bf(float f) {
    union { float f; unsigned int u; } v; v.f = f;
    unsigned int r = v.u + 0x7FFFu + ((v.u >> 16) & 1u);  // RNE
    return (unsigned short)(r >> 16);
}

static __device__ __forceinline__ f32x4 mfma16(bf16x8 a, bf16x8 b, f32x4 c) {
    return __builtin_amdgcn_mfma_f32_16x16x32_bf16(a, b, c, 0, 0, 0);
}

// pack two f32 -> one u32 of two bf16 (lo=a, hi=b); no builtin on gfx950
static __device__ __forceinline__ unsigned int cvt_pk_bf16(float a, float b) {
    unsigned int r;
    asm("v_cvt_pk_bf16_f32 %0, %1, %2" : "=v"(r) : "v"(a), "v"(b));
    return r;
}

// ---------------------------------------------------------------------------
// prep: x (B,128,4096) f32 -> t_bf (B,4096,128) bf16 ; weights f32 -> bf16
__global__ __launch_bounds__(256) void k_prep(
    const float* __restrict__ x,
    const float* __restrict__ Wq, const float* __restrict__ Wk,
    const float* __restrict__ Wv, const float* __restrict__ Wo,
    unsigned short* __restrict__ t_bf, unsigned short* __restrict__ Wb)
{
    const int bx = blockIdx.x;
    const int tid = threadIdx.x;
    if (bx >= 1024) {
        const int m = bx - 1024;
        const float* W = (m == 0) ? Wq : (m == 1) ? Wk : (m == 2) ? Wv : Wo;
        const float s = (m == 0) ? QSCALE : 1.0f;
        for (int idx = tid; idx < 16384; idx += 256)
            Wb[m * 16384 + idx] = f2bf(W[idx] * s);
        return;
    }
    __shared__ float tl[64][65];  // +1 pad: conflict-free transpose
    const int b  = bx >> 7;
    const int c0 = ((bx >> 6) & 1) * 64;
    const int n0 = (bx & 63) * 64;
    for (int idx = tid; idx < 4096; idx += 256) {
        const int ci = idx >> 6, nj = idx & 63;
        tl[ci][nj] = x[((size_t)(b * 128 + c0 + ci)) * 4096 + n0 + nj];
    }
    __syncthreads();
    for (int idx = tid; idx < 4096; idx += 256) {
        const int nj = idx >> 6, ci = idx & 63;
        t_bf[((size_t)(b * 4096 + n0 + nj)) * 128 + c0 + ci] = f2bf(tl[ci][nj]);
    }
}

// ---------------------------------------------------------------------------
// proj3: Q/K/V = t @ W^T + b.   grid (512, 3): 64 tokens/block, blockIdx.y=mat.
// Q,K stored (bh, n, 32) bf16 (Q pre-scaled). V stored transposed (bh, 32, n).
__global__ __launch_bounds__(256) void k_proj3(
    const unsigned short* __restrict__ t_bf, const unsigned short* __restrict__ Wb,
    const float* __restrict__ bq, const float* __restrict__ bk, const float* __restrict__ bv,
    unsigned short* __restrict__ Qb, unsigned short* __restrict__ Kb,
    unsigned short* __restrict__ Vt)
{
    const int mat  = blockIdx.y;
    const int widx = threadIdx.x >> 6;
    const int lane = threadIdx.x & 63;
    const int g = lane >> 4, l15 = lane & 15;
    const int row0 = blockIdx.x * 64 + widx * 16;
    const int gt_row = row0 + l15;
    const unsigned short* Wm = Wb + mat * 16384;
    const float* bias = (mat == 0) ? bq : (mat == 1) ? bk : bv;

    bf16x8 tf[4];
    #pragma unroll
    for (int kc = 0; kc < 4; ++kc)
        tf[kc] = *(const bf16x8*)(t_bf + (size_t)gt_row * 128 + kc * 32 + g * 8);

    #pragma unroll
    for (int ot = 0; ot < 8; ++ot) {
        f32x4 acc;
        if (mat < 2) {
            float bb = bias[ot * 16 + l15];
            if (mat == 0) bb *= QSCALE;
            acc[0] = bb; acc[1] = bb; acc[2] = bb; acc[3] = bb;
        } else {
            #pragma unroll
            for (int r = 0; r < 4; ++r) acc[r] = bias[ot * 16 + 4 * g + r];
        }
        #pragma unroll
        for (int kc = 0; kc < 4; ++kc) {
            bf16x8 wf = *(const bf16x8*)(Wm + (size_t)(ot * 16 + l15) * 128 + kc * 32 + g * 8);
            acc = (mat == 2) ? mfma16(wf, tf[kc], acc) : mfma16(tf[kc], wf, acc);
        }
        if (mat < 2) {
            unsigned short* dst = (mat == 0) ? Qb : Kb;
            const int o = ot * 16 + l15, h = o >> 5, d = o & 31;
            #pragma unroll
            for (int r = 0; r < 4; ++r) {
                const int gt = row0 + 4 * g + r;
                const int b = gt >> 12, n = gt & 4095;
                dst[(((size_t)(b * 4 + h)) * 4096 + n) * 32 + d] = f2bf(acc[r]);
            }
        } else {
            const int b = gt_row >> 12, n = gt_row & 4095;
            #pragma unroll
            for (int r = 0; r < 4; ++r) {
                const int o = ot * 16 + 4 * g + r, h = o >> 5, d = o & 31;
                Vt[(((size_t)(b * 4 + h)) * 32 + d) * 4096 + n] = f2bf(acc[r]);
            }
        }
    }
}

// ---------------------------------------------------------------------------
// attn: flash attention. 1 wave = 32 q rows of one (b,h); KVBLK=32.
// Swapped QK^T: mfma(K,Q) -> lane(g,l15) reg r = S[q0(+16)+l15][kv0(+16)+4g+r].
// P packed in-register into PV A-frag with slot map pi(g,j)=16*(j>>2)+4g+(j&3);
// V B-frag uses the identical map -> permutation cancels inside MFMA.
// Denominator = extra PV MFMA against constant-1.0 B operand (acc2*).
// Defer-max: cross-lane reduce + rescale only when a row max grows by > THR.
__global__ __launch_bounds__(256) void k_attn(
    const unsigned short* __restrict__ Qb, const unsigned short* __restrict__ Kb,
    const unsigned short* __restrict__ Vt, unsigned short* __restrict__ Ob)
{
    const int wg = blockIdx.x * 4 + (threadIdx.x >> 6);  // 4096 waves total
    const int bh = wg >> 7, q0 = (wg & 127) * 32;        // 128 q-tiles per bh
    const int lane = threadIdx.x & 63, g = lane >> 4, l15 = lane & 15;

    const bf16x8 qf0 = *(const bf16x8*)(Qb + ((size_t)bh * 4096 + q0 + l15) * 32 + g * 8);
    const bf16x8 qf1 = *(const bf16x8*)(Qb + ((size_t)bh * 4096 + q0 + 16 + l15) * 32 + g * 8);
    const unsigned short* Kbh = Kb + (size_t)bh * 131072;
    const unsigned short* Vbh = Vt + (size_t)bh * 131072;

    bf16x8 onesf;
    #pragma unroll
    for (int j = 0; j < 8; ++j) onesf[j] = (short)0x3F80;  // bf16 1.0

    f32x4 acc00 = {0.f,0.f,0.f,0.f}, acc01 = {0.f,0.f,0.f,0.f};
    f32x4 acc10 = {0.f,0.f,0.f,0.f}, acc11 = {0.f,0.f,0.f,0.f};
    f32x4 acc20 = {0.f,0.f,0.f,0.f}, acc21 = {0.f,0.f,0.f,0.f};
    float m0 = -1e30f, m1 = -1e30f;
    float nm0 = 0.f, nm1 = 0.f;  // -m*LOG2E, refreshed on every m update
    const f32x4 z = {0.f,0.f,0.f,0.f};

#define LOAD_KV(KV, KF0, KF1, V00, V01, V10, V11)                              \
    {                                                                          \
      const unsigned short* kp = Kbh + (size_t)((KV) + l15) * 32 + g * 8;      \
      KF0 = *(const bf16x8*)(kp);                                              \
      KF1 = *(const bf16x8*)(kp + 512);                                        \
      const unsigned short* vp = Vbh + (size_t)l15 * 4096 + (KV) + 4 * g;      \
      V00 = *(const s16x4*)(vp);          V01 = *(const s16x4*)(vp + 16);      \
      V10 = *(const s16x4*)(vp + 65536);  V11 = *(const s16x4*)(vp + 65552);   \
    }

#define ATTN_STEP(KF0, KF1, V00, V01, V10, V11)                                \
    {                                                                          \
      f32x4 s00 = mfma16(KF0, qf0, z), s01 = mfma16(KF1, qf0, z);              \
      f32x4 s10 = mfma16(KF0, qf1, z), s11 = mfma16(KF1, qf1, z);              \
      float lm0 = fmaxf(fmaxf(fmaxf(s00[0], s00[1]), fmaxf(s00[2], s00[3])),   \
                        fmaxf(fmaxf(s01[0], s01[1]), fmaxf(s01[2], s01[3])));  \
      float lm1 = fmaxf(fmaxf(fmaxf(s10[0], s10[1]), fmaxf(s10[2], s10[3])),   \
                        fmaxf(fmaxf(s11[0], s11[1]), fmaxf(s11[2], s11[3])));  \
      if (!__all((lm0 <= m0 + THR) && (lm1 <= m1 + THR))) {                    \
        float rm0 = fmaxf(lm0, __shfl_xor(lm0, 16));                           \
        rm0 = fmaxf(rm0, __shfl_xor(rm0, 32));                                 \
        float rm1 = fmaxf(lm1, __shfl_xor(lm1, 16));                           \
        rm1 = fmaxf(rm1, __shfl_xor(rm1, 32));                                 \
        const float m0n = fmaxf(m0, rm0), m1n = fmaxf(m1, rm1);                \
        const float sc0 = exp2f((m0 - m0n) * LOG2E);                           \
        const float sc1 = exp2f((m1 - m1n) * LOG2E);                           \
        m0 = m0n; m1 = m1n; nm0 = -m0 * LOG2E; nm1 = -m1 * LOG2E;              \
        _Pragma("unroll")                                                      \
        for (int r = 0; r < 4; ++r) {                                          \
          const float f0 = __shfl(sc0, 4 * g + r);                             \
          const float f1 = __shfl(sc1, 4 * g + r);                             \
          acc00[r] *= f0; acc01[r] *= f0; acc20[r] *= f0;                      \
          acc10[r] *= f1; acc11[r] *= f1; acc21[r] *= f1;                      \
        }                                                                      \
      }                                                                        \
      float p0[8], p1[8];                                                      \
      _Pragma("unroll")                                                        \
      for (int i = 0; i < 4; ++i) {                                            \
        p0[i]     = exp2f(fmaf(s00[i], LOG2E, nm0));                           \
        p0[4 + i] = exp2f(fmaf(s01[i], LOG2E, nm0));                           \
        p1[i]     = exp2f(fmaf(s10[i], LOG2E, nm1));                           \
        p1[4 + i] = exp2f(fmaf(s11[i], LOG2E, nm1));                           \
      }                                                                        \
      union { bf16x8 v; unsigned int w[4]; } pa0, pa1;                         \
      pa0.w[0] = cvt_pk_bf16(p0[0], p0[1]); pa0.w[1] = cvt_pk_bf16(p0[2], p0[3]); \
      pa0.w[2] = cvt_pk_bf16(p0[4], p0[5]); pa0.w[3] = cvt_pk_bf16(p0[6], p0[7]); \
      pa1.w[0] = cvt_pk_bf16(p1[0], p1[1]); pa1.w[1] = cvt_pk_bf16(p1[2], p1[3]); \
      pa1.w[2] = cvt_pk_bf16(p1[4], p1[5]); pa1.w[3] = cvt_pk_bf16(p1[6], p1[7]); \
      union { bf16x8 v; s16x4 h[2]; } vf0, vf1;                                \
      vf0.h[0] = V00; vf0.h[1] = V01;                                          \
      vf1.h[0] = V10; vf1.h[1] = V11;                                          \
      acc00 = mfma16(pa0.v, vf0.v, acc00);                                     \
      acc01 = mfma16(pa0.v, vf1.v, acc01);                                     \
      acc20 = mfma16(pa0.v, onesf, acc20);                                     \
      acc10 = mfma16(pa1.v, vf0.v, acc10);                                     \
      acc11 = mfma16(pa1.v, vf1.v, acc11);                                     \
      acc21 = mfma16(pa1.v, onesf, acc21);                                     \
    }

    bf16x8 kA0, kA1, kB0, kB1;
    s16x4 vA00, vA01, vA10, vA11, vB00, vB01, vB10, vB11;

    LOAD_KV(0, kA0, kA1, vA00, vA01, vA10, vA11);
    for (int it = 0; it < 128; it += 2) {
        const int kvB = (it * 32 + 32) & 4095;
        LOAD_KV(kvB, kB0, kB1, vB00, vB01, vB10, vB11);
        ATTN_STEP(kA0, kA1, vA00, vA01, vA10, vA11);
        const int kvA = (it * 32 + 64) & 4095;  // wraps to 0 on last pair (dead load)
        LOAD_KV(kvA, kA0, kA1, vA00, vA01, vA10, vA11);
        ATTN_STEP(kB0, kB1, vB00, vB01, vB10, vB11);
    }
#undef LOAD_KV
#undef ATTN_STEP

    const int b = bh >> 2, h = bh & 3;
    #pragma unroll
    for (int r = 0; r < 4; ++r) {
        const float r0 = 1.0f / acc20[r];  // denom for row q0+4g+r (all cols equal)
        const float r1 = 1.0f / acc21[r];  // denom for row q0+16+4g+r
        const size_t base0 = ((size_t)b * 4096 + q0 + 4 * g + r) * 128 + h * 32;
        const size_t base1 = ((size_t)b * 4096 + q0 + 16 + 4 * g + r) * 128 + h * 32;
        Ob[base0 + l15]      = f2bf(acc00[r] * r0);
        Ob[base0 + 16 + l15] = f2bf(acc01[r] * r0);
        Ob[base1 + l15]      = f2bf(acc10[r] * r1);
        Ob[base1 + 16 + l15] = f2bf(acc11[r] * r1);
    }
}

// ---------------------------------------------------------------------------
// projo: out(b,c,n) = (O @ Wo^T + bo)^T via swapped MFMA (A=Wo rows, B=O rows)
__global__ __launch_bounds__(256) void k_projo(
    const unsigned short* __restrict__ Ob, const unsigned short* __restrict__ Wob,
    const float* __restrict__ bo, float* __restrict__ out)
{
    const int widx = threadIdx.x >> 6;
    const int lane = threadIdx.x & 63, g = lane >> 4, l15 = lane & 15;
    const int gt = blockIdx.x * 64 + widx * 16 + l15;  // token (col of D)
    const int b = gt >> 12, n = gt & 4095;

    bf16x8 of[4];
    #pragma unroll
    for (int kc = 0; kc < 4; ++kc)
        of[kc] = *(const bf16x8*)(Ob + (size_t)gt * 128 + kc * 32 + g * 8);

    #pragma unroll
    for (int ot = 0; ot < 8; ++ot) {
        f32x4 acc;
        #pragma unroll
        for (int r = 0; r < 4; ++r) acc[r] = bo[ot * 16 + 4 * g + r];
        #pragma unroll
        for (int kc = 0; kc < 4; ++kc) {
            bf16x8 wf = *(const bf16x8*)(Wob + (size_t)(ot * 16 + l15) * 128 + kc * 32 + g * 8);
            acc = mfma16(wf, of[kc], acc);
        }
        #pragma unroll
        for (int r = 0; r < 4; ++r)
            out[((size_t)b * 128 + ot * 16 + 4 * g + r) * 4096 + n] = acc[r];
    }
}

// ---------------------------------------------------------------------------
extern "C" void kernel_launch(void* const* d_in, const int* in_sizes, int n_in,
                              void* d_out, int out_size, void* d_ws, size_t ws_size,
                              hipStream_t stream)
{
    const float* x  = (const float*)d_in[0];
    const float* Wq = (const float*)d_in[1];
    const float* bq = (const float*)d_in[2];
    const float* Wk = (const float*)d_in[3];
    const float* bk = (const float*)d_in[4];
    const float* Wv = (const float*)d_in[5];
    const float* bv = (const float*)d_in[6];
    const float* Wo = (const float*)d_in[7];
    const float* bo = (const float*)d_in[8];
    float* out = (float*)d_out;

    char* ws = (char*)d_ws;
    unsigned short* t_bf = (unsigned short*)(ws);             //  8,388,608 B
    unsigned short* Wb   = (unsigned short*)(ws +  8388608);  //    131,072 B
    unsigned short* Qb   = (unsigned short*)(ws +  8519680);  //  8,388,608 B
    unsigned short* Kb   = (unsigned short*)(ws + 16908288);  //  8,388,608 B
    unsigned short* Vt   = (unsigned short*)(ws + 25296896);  //  8,388,608 B
    unsigned short* Ob   = (unsigned short*)(ws + 33685504);  //  8,388,608 B -> 42.1 MB total

    k_prep <<<dim3(1028),     dim3(256), 0, stream>>>(x, Wq, Wk, Wv, Wo, t_bf, Wb);
    k_proj3<<<dim3(512, 3),   dim3(256), 0, stream>>>(t_bf, Wb, bq, bk, bv, Qb, Kb, Vt);
    k_attn <<<dim3(1024),     dim3(256), 0, stream>>>(Qb, Kb, Vt, Ob);
    k_projo<<<dim3(512),      dim3(256), 0, stream>>>(Ob, Wb + 3 * 16384, bo, out);
}

// Round 3
// 346.267 us; speedup vs baseline: 1.9764x; 1.1919x over previous
//
#include <hip/hip_runtime.h>

// MultiHeadSelfAttention2D: B=8, C=128, H=W=64, N=4096, heads=4, hd=32
// Pipeline: prep (transpose x -> tokens bf16, weights -> bf16)
//           proj3 (QKV via MFMA; V written transposed)
//           attn  (flash attention, split-KV: 2 waves per 32-row q-tile,
//                  each covers 2048 KV; defer-max + ones-column denominator +
//                  cvt_pk pack + reg prefetch; LDS merge of the two halves)
//           projo (output projection, transposed store)

using f32x4  = __attribute__((ext_vector_type(4))) float;
using bf16x8 = __attribute__((ext_vector_type(8))) short;  // 8 bf16 in 4 VGPRs
using s16x4  = __attribute__((ext_vector_type(4))) short;

#define QSCALE 0.17677669529663687f  // 1/sqrt(32), folded into Wq/bq
#define LOG2E  1.4426950408889634f
#define THR    8.0f                  // defer-max threshold (natural-log units)

static __device__ __forceinline__ unsigned short f2bf(float f) {
    union { float f; unsigned int u; } v; v.f = f;
    unsigned int r = v.u + 0x7FFFu + ((v.u >> 16) & 1u);  // RNE
    return (unsigned short)(r >> 16);
}

static __device__ __forceinline__ f32x4 mfma16(bf16x8 a, bf16x8 b, f32x4 c) {
    return __builtin_amdgcn_mfma_f32_16x16x32_bf16(a, b, c, 0, 0, 0);
}

// pack two f32 -> one u32 of two bf16 (lo=a, hi=b); no builtin on gfx950
static __device__ __forceinline__ unsigned int cvt_pk_bf16(float a, float b) {
    unsigned int r;
    asm("v_cvt_pk_bf16_f32 %0, %1, %2" : "=v"(r) : "v"(a), "v"(b));
    return r;
}

// ---------------------------------------------------------------------------
// prep: x (B,128,4096) f32 -> t_bf (B,4096,128) bf16 ; weights f32 -> bf16
__global__ __launch_bounds__(256) void k_prep(
    const float* __restrict__ x,
    const float* __restrict__ Wq, const float* __restrict__ Wk,
    const float* __restrict__ Wv, const float* __restrict__ Wo,
    unsigned short* __restrict__ t_bf, unsigned short* __restrict__ Wb)
{
    const int bx = blockIdx.x;
    const int tid = threadIdx.x;
    if (bx >= 1024) {
        const int m = bx - 1024;
        const float* W = (m == 0) ? Wq : (m == 1) ? Wk : (m == 2) ? Wv : Wo;
        const float s = (m == 0) ? QSCALE : 1.0f;
        for (int idx = tid; idx < 16384; idx += 256)
            Wb[m * 16384 + idx] = f2bf(W[idx] * s);
        return;
    }
    __shared__ float tl[64][65];  // +1 pad: conflict-free transpose
    const int b  = bx >> 7;
    const int c0 = ((bx >> 6) & 1) * 64;
    const int n0 = (bx & 63) * 64;
    for (int idx = tid; idx < 4096; idx += 256) {
        const int ci = idx >> 6, nj = idx & 63;
        tl[ci][nj] = x[((size_t)(b * 128 + c0 + ci)) * 4096 + n0 + nj];
    }
    __syncthreads();
    for (int idx = tid; idx < 4096; idx += 256) {
        const int nj = idx >> 6, ci = idx & 63;
        t_bf[((size_t)(b * 4096 + n0 + nj)) * 128 + c0 + ci] = f2bf(tl[ci][nj]);
    }
}

// ---------------------------------------------------------------------------
// proj3: Q/K/V = t @ W^T + b.   grid (512, 3): 64 tokens/block, blockIdx.y=mat.
// Q,K stored (bh, n, 32) bf16 (Q pre-scaled). V stored transposed (bh, 32, n).
__global__ __launch_bounds__(256) void k_proj3(
    const unsigned short* __restrict__ t_bf, const unsigned short* __restrict__ Wb,
    const float* __restrict__ bq, const float* __restrict__ bk, const float* __restrict__ bv,
    unsigned short* __restrict__ Qb, unsigned short* __restrict__ Kb,
    unsigned short* __restrict__ Vt)
{
    const int mat  = blockIdx.y;
    const int widx = threadIdx.x >> 6;
    const int lane = threadIdx.x & 63;
    const int g = lane >> 4, l15 = lane & 15;
    const int row0 = blockIdx.x * 64 + widx * 16;
    const int gt_row = row0 + l15;
    const unsigned short* Wm = Wb + mat * 16384;
    const float* bias = (mat == 0) ? bq : (mat == 1) ? bk : bv;

    bf16x8 tf[4];
    #pragma unroll
    for (int kc = 0; kc < 4; ++kc)
        tf[kc] = *(const bf16x8*)(t_bf + (size_t)gt_row * 128 + kc * 32 + g * 8);

    #pragma unroll
    for (int ot = 0; ot < 8; ++ot) {
        f32x4 acc;
        if (mat < 2) {
            float bb = bias[ot * 16 + l15];
            if (mat == 0) bb *= QSCALE;
            acc[0] = bb; acc[1] = bb; acc[2] = bb; acc[3] = bb;
        } else {
            #pragma unroll
            for (int r = 0; r < 4; ++r) acc[r] = bias[ot * 16 + 4 * g + r];
        }
        #pragma unroll
        for (int kc = 0; kc < 4; ++kc) {
            bf16x8 wf = *(const bf16x8*)(Wm + (size_t)(ot * 16 + l15) * 128 + kc * 32 + g * 8);
            acc = (mat == 2) ? mfma16(wf, tf[kc], acc) : mfma16(tf[kc], wf, acc);
        }
        if (mat < 2) {
            unsigned short* dst = (mat == 0) ? Qb : Kb;
            const int o = ot * 16 + l15, h = o >> 5, d = o & 31;
            #pragma unroll
            for (int r = 0; r < 4; ++r) {
                const int gt = row0 + 4 * g + r;
                const int b = gt >> 12, n = gt & 4095;
                dst[(((size_t)(b * 4 + h)) * 4096 + n) * 32 + d] = f2bf(acc[r]);
            }
        } else {
            const int b = gt_row >> 12, n = gt_row & 4095;
            #pragma unroll
            for (int r = 0; r < 4; ++r) {
                const int o = ot * 16 + 4 * g + r, h = o >> 5, d = o & 31;
                Vt[(((size_t)(b * 4 + h)) * 32 + d) * 4096 + n] = f2bf(acc[r]);
            }
        }
    }
}

// ---------------------------------------------------------------------------
// attn: flash attention, split-KV. Block = 4 waves = 2 q-tiles x 2 KV halves.
// Wave (qt, half): 32 q rows, KV in [half*2048, half*2048+2048), KVBLK=32.
// Swapped QK^T: mfma(K,Q) -> lane(g,l15) reg r = S[q=l15][kv0(+16)+4g+r].
// P packed in-register into PV A-frag with slot map pi(g,j)=16*(j>>2)+4g+(j&3);
// V B-frag uses the identical map -> permutation cancels inside MFMA.
// Denominator = extra PV MFMA against constant-1.0 B operand (acc2*).
// Defer-max: cross-lane reduce + rescale only when a row max grows by > THR.
// Halves merged through LDS (exact online-softmax combine), wave half==0 writes.
__global__ __launch_bounds__(256) void k_attn(
    const unsigned short* __restrict__ Qb, const unsigned short* __restrict__ Kb,
    const unsigned short* __restrict__ Vt, unsigned short* __restrict__ Ob)
{
    const int widx = threadIdx.x >> 6;
    const int qt   = widx >> 1;          // q-tile within block (0,1)
    const int half = widx & 1;           // KV half (0,1)
    const int qtg  = blockIdx.x * 2 + qt;
    const int bh = qtg >> 7, q0 = (qtg & 127) * 32;
    const int lane = threadIdx.x & 63, g = lane >> 4, l15 = lane & 15;
    const int kvbase = half * 2048;

    __shared__ float lacc[2][32][36];   // [qt][col d][row q], padded
    __shared__ float lmm[2][32];        // [qt][row q] running max (half 1)
    __shared__ float lden[2][32];       // [qt][row q] denominator (half 1)

    const bf16x8 qf0 = *(const bf16x8*)(Qb + ((size_t)bh * 4096 + q0 + l15) * 32 + g * 8);
    const bf16x8 qf1 = *(const bf16x8*)(Qb + ((size_t)bh * 4096 + q0 + 16 + l15) * 32 + g * 8);
    const unsigned short* Kbh = Kb + (size_t)bh * 131072;
    const unsigned short* Vbh = Vt + (size_t)bh * 131072;

    bf16x8 onesf;
    #pragma unroll
    for (int j = 0; j < 8; ++j) onesf[j] = (short)0x3F80;  // bf16 1.0

    f32x4 acc00 = {0.f,0.f,0.f,0.f}, acc01 = {0.f,0.f,0.f,0.f};
    f32x4 acc10 = {0.f,0.f,0.f,0.f}, acc11 = {0.f,0.f,0.f,0.f};
    f32x4 acc20 = {0.f,0.f,0.f,0.f}, acc21 = {0.f,0.f,0.f,0.f};
    float m0 = -1e30f, m1 = -1e30f;
    float nm0 = 0.f, nm1 = 0.f;  // -m*LOG2E, refreshed on every m update
    const f32x4 z = {0.f,0.f,0.f,0.f};

#define LOAD_KV(KV, KF0, KF1, V00, V01, V10, V11)                              \
    {                                                                          \
      const unsigned short* kp = Kbh + (size_t)((KV) + l15) * 32 + g * 8;      \
      KF0 = *(const bf16x8*)(kp);                                              \
      KF1 = *(const bf16x8*)(kp + 512);                                        \
      const unsigned short* vp = Vbh + (size_t)l15 * 4096 + (KV) + 4 * g;      \
      V00 = *(const s16x4*)(vp);          V01 = *(const s16x4*)(vp + 16);      \
      V10 = *(const s16x4*)(vp + 65536);  V11 = *(const s16x4*)(vp + 65552);   \
    }

#define ATTN_STEP(KF0, KF1, V00, V01, V10, V11)                                \
    {                                                                          \
      f32x4 s00 = mfma16(KF0, qf0, z), s01 = mfma16(KF1, qf0, z);              \
      f32x4 s10 = mfma16(KF0, qf1, z), s11 = mfma16(KF1, qf1, z);              \
      float lm0 = fmaxf(fmaxf(fmaxf(s00[0], s00[1]), fmaxf(s00[2], s00[3])),   \
                        fmaxf(fmaxf(s01[0], s01[1]), fmaxf(s01[2], s01[3])));  \
      float lm1 = fmaxf(fmaxf(fmaxf(s10[0], s10[1]), fmaxf(s10[2], s10[3])),   \
                        fmaxf(fmaxf(s11[0], s11[1]), fmaxf(s11[2], s11[3])));  \
      if (!__all((lm0 <= m0 + THR) && (lm1 <= m1 + THR))) {                    \
        float rm0 = fmaxf(lm0, __shfl_xor(lm0, 16));                           \
        rm0 = fmaxf(rm0, __shfl_xor(rm0, 32));                                 \
        float rm1 = fmaxf(lm1, __shfl_xor(lm1, 16));                           \
        rm1 = fmaxf(rm1, __shfl_xor(rm1, 32));                                 \
        const float m0n = fmaxf(m0, rm0), m1n = fmaxf(m1, rm1);                \
        const float sc0 = exp2f((m0 - m0n) * LOG2E);                           \
        const float sc1 = exp2f((m1 - m1n) * LOG2E);                           \
        m0 = m0n; m1 = m1n; nm0 = -m0 * LOG2E; nm1 = -m1 * LOG2E;              \
        _Pragma("unroll")                                                      \
        for (int r = 0; r < 4; ++r) {                                          \
          const float f0 = __shfl(sc0, 4 * g + r);                             \
          const float f1 = __shfl(sc1, 4 * g + r);                             \
          acc00[r] *= f0; acc01[r] *= f0; acc20[r] *= f0;                      \
          acc10[r] *= f1; acc11[r] *= f1; acc21[r] *= f1;                      \
        }                                                                      \
      }                                                                        \
      float p0[8], p1[8];                                                      \
      _Pragma("unroll")                                                        \
      for (int i = 0; i < 4; ++i) {                                            \
        p0[i]     = exp2f(fmaf(s00[i], LOG2E, nm0));                           \
        p0[4 + i] = exp2f(fmaf(s01[i], LOG2E, nm0));                           \
        p1[i]     = exp2f(fmaf(s10[i], LOG2E, nm1));                           \
        p1[4 + i] = exp2f(fmaf(s11[i], LOG2E, nm1));                           \
      }                                                                        \
      union { bf16x8 v; unsigned int w[4]; } pa0, pa1;                         \
      pa0.w[0] = cvt_pk_bf16(p0[0], p0[1]); pa0.w[1] = cvt_pk_bf16(p0[2], p0[3]); \
      pa0.w[2] = cvt_pk_bf16(p0[4], p0[5]); pa0.w[3] = cvt_pk_bf16(p0[6], p0[7]); \
      pa1.w[0] = cvt_pk_bf16(p1[0], p1[1]); pa1.w[1] = cvt_pk_bf16(p1[2], p1[3]); \
      pa1.w[2] = cvt_pk_bf16(p1[4], p1[5]); pa1.w[3] = cvt_pk_bf16(p1[6], p1[7]); \
      union { bf16x8 v; s16x4 h[2]; } vf0, vf1;                                \
      vf0.h[0] = V00; vf0.h[1] = V01;                                          \
      vf1.h[0] = V10; vf1.h[1] = V11;                                          \
      acc00 = mfma16(pa0.v, vf0.v, acc00);                                     \
      acc01 = mfma16(pa0.v, vf1.v, acc01);                                     \
      acc20 = mfma16(pa0.v, onesf, acc20);                                     \
      acc10 = mfma16(pa1.v, vf0.v, acc10);                                     \
      acc11 = mfma16(pa1.v, vf1.v, acc11);                                     \
      acc21 = mfma16(pa1.v, onesf, acc21);                                     \
    }

    bf16x8 kA0, kA1, kB0, kB1;
    s16x4 vA00, vA01, vA10, vA11, vB00, vB01, vB10, vB11;

    LOAD_KV(kvbase, kA0, kA1, vA00, vA01, vA10, vA11);
    for (int it = 0; it < 64; it += 2) {
        const int kvB = kvbase + ((it * 32 + 32) & 2047);
        LOAD_KV(kvB, kB0, kB1, vB00, vB01, vB10, vB11);
        ATTN_STEP(kA0, kA1, vA00, vA01, vA10, vA11);
        const int kvA = kvbase + ((it * 32 + 64) & 2047);  // wraps (dead load)
        LOAD_KV(kvA, kA0, kA1, vA00, vA01, vA10, vA11);
        ATTN_STEP(kB0, kB1, vB00, vB01, vB10, vB11);
    }
#undef LOAD_KV
#undef ATTN_STEP

    // ---- merge the two KV halves (exact online-softmax combine) -----------
    if (half == 1) {
        *(f32x4*)&lacc[qt][l15][4 * g]           = acc00;  // rows 0..15, col l15
        *(f32x4*)&lacc[qt][16 + l15][4 * g]      = acc01;  // cols 16..31
        *(f32x4*)&lacc[qt][l15][16 + 4 * g]      = acc10;  // rows 16..31
        *(f32x4*)&lacc[qt][16 + l15][16 + 4 * g] = acc11;
        if (l15 == 0) {
            #pragma unroll
            for (int r = 0; r < 4; ++r) {
                lden[qt][4 * g + r]      = acc20[r];
                lden[qt][16 + 4 * g + r] = acc21[r];
            }
        }
        if (g == 0) { lmm[qt][l15] = m0; lmm[qt][16 + l15] = m1; }
    }
    __syncthreads();
    if (half == 1) return;

    const int b = bh >> 2, h = bh & 3;
    #pragma unroll
    for (int r = 0; r < 4; ++r) {
        const int row0 = 4 * g + r, row1 = 16 + 4 * g + r;
        const float ms0 = __shfl(m0, row0);   // own max for row q0+row0
        const float ms1 = __shfl(m1, row0);   // own max for row q0+row1
        const float mo0 = lmm[qt][row0], mo1 = lmm[qt][row1];
        const float mx0 = fmaxf(ms0, mo0), mx1 = fmaxf(ms1, mo1);
        const float fs0 = exp2f((ms0 - mx0) * LOG2E), fo0 = exp2f((mo0 - mx0) * LOG2E);
        const float fs1 = exp2f((ms1 - mx1) * LOG2E), fo1 = exp2f((mo1 - mx1) * LOG2E);
        const float rd0 = 1.0f / (acc20[r] * fs0 + lden[qt][row0] * fo0);
        const float rd1 = 1.0f / (acc21[r] * fs1 + lden[qt][row1] * fo1);
        const float o00 = acc00[r] * fs0 + lacc[qt][l15][row0] * fo0;
        const float o01 = acc01[r] * fs0 + lacc[qt][16 + l15][row0] * fo0;
        const float o10 = acc10[r] * fs1 + lacc[qt][l15][row1] * fo1;
        const float o11 = acc11[r] * fs1 + lacc[qt][16 + l15][row1] * fo1;
        const size_t base0 = ((size_t)b * 4096 + q0 + row0) * 128 + h * 32;
        const size_t base1 = ((size_t)b * 4096 + q0 + row1) * 128 + h * 32;
        Ob[base0 + l15]      = f2bf(o00 * rd0);
        Ob[base0 + 16 + l15] = f2bf(o01 * rd0);
        Ob[base1 + l15]      = f2bf(o10 * rd1);
        Ob[base1 + 16 + l15] = f2bf(o11 * rd1);
    }
}

// ---------------------------------------------------------------------------
// projo: out(b,c,n) = (O @ Wo^T + bo)^T via swapped MFMA (A=Wo rows, B=O rows)
__global__ __launch_bounds__(256) void k_projo(
    const unsigned short* __restrict__ Ob, const unsigned short* __restrict__ Wob,
    const float* __restrict__ bo, float* __restrict__ out)
{
    const int widx = threadIdx.x >> 6;
    const int lane = threadIdx.x & 63, g = lane >> 4, l15 = lane & 15;
    const int gt = blockIdx.x * 64 + widx * 16 + l15;  // token (col of D)
    const int b = gt >> 12, n = gt & 4095;

    bf16x8 of[4];
    #pragma unroll
    for (int kc = 0; kc < 4; ++kc)
        of[kc] = *(const bf16x8*)(Ob + (size_t)gt * 128 + kc * 32 + g * 8);

    #pragma unroll
    for (int ot = 0; ot < 8; ++ot) {
        f32x4 acc;
        #pragma unroll
        for (int r = 0; r < 4; ++r) acc[r] = bo[ot * 16 + 4 * g + r];
        #pragma unroll
        for (int kc = 0; kc < 4; ++kc) {
            bf16x8 wf = *(const bf16x8*)(Wob + (size_t)(ot * 16 + l15) * 128 + kc * 32 + g * 8);
            acc = mfma16(wf, of[kc], acc);
        }
        #pragma unroll
        for (int r = 0; r < 4; ++r)
            out[((size_t)b * 128 + ot * 16 + 4 * g + r) * 4096 + n] = acc[r];
    }
}

// ---------------------------------------------------------------------------
extern "C" void kernel_launch(void* const* d_in, const int* in_sizes, int n_in,
                              void* d_out, int out_size, void* d_ws, size_t ws_size,
                              hipStream_t stream)
{
    const float* x  = (const float*)d_in[0];
    const float* Wq = (const float*)d_in[1];
    const float* bq = (const float*)d_in[2];
    const float* Wk = (const float*)d_in[3];
    const float* bk = (const float*)d_in[4];
    const float* Wv = (const float*)d_in[5];
    const float* bv = (const float*)d_in[6];
    const float* Wo = (const float*)d_in[7];
    const float* bo = (const float*)d_in[8];
    float* out = (float*)d_out;

    char* ws = (char*)d_ws;
    unsigned short* t_bf = (unsigned short*)(ws);             //  8,388,608 B
    unsigned short* Wb   = (unsigned short*)(ws +  8388608);  //    131,072 B
    unsigned short* Qb   = (unsigned short*)(ws +  8519680);  //  8,388,608 B
    unsigned short* Kb   = (unsigned short*)(ws + 16908288);  //  8,388,608 B
    unsigned short* Vt   = (unsigned short*)(ws + 25296896);  //  8,388,608 B
    unsigned short* Ob   = (unsigned short*)(ws + 33685504);  //  8,388,608 B -> 42.1 MB total

    k_prep <<<dim3(1028),     dim3(256), 0, stream>>>(x, Wq, Wk, Wv, Wo, t_bf, Wb);
    k_proj3<<<dim3(512, 3),   dim3(256), 0, stream>>>(t_bf, Wb, bq, bk, bv, Qb, Kb, Vt);
    k_attn <<<dim3(2048),     dim3(256), 0, stream>>>(Qb, Kb, Vt, Ob);
    k_projo<<<dim3(512),      dim3(256), 0, stream>>>(Ob, Wb + 3 * 16384, bo, out);
}

// Round 4
// 233.566 us; speedup vs baseline: 2.9301x; 1.4825x over previous
//
#include <hip/hip_runtime.h>

// MultiHeadSelfAttention2D: B=8, C=128, H=W=64, N=4096, heads=4, hd=32
// Pipeline: prep (transpose x -> tokens bf16, weights -> bf16; Wq pre-scaled
//                 by 1/sqrt(32)*log2(e) so QK^T lands in the exp2 domain)
//           proj3 (QKV via MFMA; V written in (bh, kvblk, d, kv%32) layout)
//           attn  (flash attention, split-KV, MAX-FREE softmax:
//                  p = exp2(S) directly; denominator via ones-column MFMA;
//                  merge halves by plain accumulator addition)
//           projo (output projection, transposed store)

using f32x4  = __attribute__((ext_vector_type(4))) float;
using bf16x8 = __attribute__((ext_vector_type(8))) short;  // 8 bf16 in 4 VGPRs
using s16x4  = __attribute__((ext_vector_type(4))) short;

#define QSCALE 0.17677669529663687f  // 1/sqrt(32)
#define LOG2E  1.4426950408889634f
#define QKS    (QSCALE * LOG2E)      // folded into Wq/bq -> S = logit*log2e

static __device__ __forceinline__ unsigned short f2bf(float f) {
    union { float f; unsigned int u; } v; v.f = f;
    unsigned int r = v.u + 0x7FFFu + ((v.u >> 16) & 1u);  // RNE
    return (unsigned short)(r >> 16);
}

static __device__ __forceinline__ f32x4 mfma16(bf16x8 a, bf16x8 b, f32x4 c) {
    return __builtin_amdgcn_mfma_f32_16x16x32_bf16(a, b, c, 0, 0, 0);
}

// pack two f32 -> one u32 of two bf16 (lo=a, hi=b); no builtin on gfx950
static __device__ __forceinline__ unsigned int cvt_pk_bf16(float a, float b) {
    unsigned int r;
    asm("v_cvt_pk_bf16_f32 %0, %1, %2" : "=v"(r) : "v"(a), "v"(b));
    return r;
}

// ---------------------------------------------------------------------------
// prep: x (B,128,4096) f32 -> t_bf (B,4096,128) bf16 ; weights f32 -> bf16
__global__ __launch_bounds__(256) void k_prep(
    const float* __restrict__ x,
    const float* __restrict__ Wq, const float* __restrict__ Wk,
    const float* __restrict__ Wv, const float* __restrict__ Wo,
    unsigned short* __restrict__ t_bf, unsigned short* __restrict__ Wb)
{
    const int bx = blockIdx.x;
    const int tid = threadIdx.x;
    if (bx >= 1024) {
        const int m = bx - 1024;
        const float* W = (m == 0) ? Wq : (m == 1) ? Wk : (m == 2) ? Wv : Wo;
        const float s = (m == 0) ? QKS : 1.0f;
        for (int idx = tid; idx < 16384; idx += 256)
            Wb[m * 16384 + idx] = f2bf(W[idx] * s);
        return;
    }
    __shared__ float tl[64][65];  // +1 pad: conflict-free transpose
    const int b  = bx >> 7;
    const int c0 = ((bx >> 6) & 1) * 64;
    const int n0 = (bx & 63) * 64;
    for (int idx = tid; idx < 4096; idx += 256) {
        const int ci = idx >> 6, nj = idx & 63;
        tl[ci][nj] = x[((size_t)(b * 128 + c0 + ci)) * 4096 + n0 + nj];
    }
    __syncthreads();
    for (int idx = tid; idx < 4096; idx += 256) {
        const int nj = idx >> 6, ci = idx & 63;
        t_bf[((size_t)(b * 4096 + n0 + nj)) * 128 + c0 + ci] = f2bf(tl[ci][nj]);
    }
}

// ---------------------------------------------------------------------------
// proj3: Q/K/V = t @ W^T + b.   grid (512, 3): 64 tokens/block, blockIdx.y=mat.
// Q,K stored (bh, n, 32) bf16 (Q pre-scaled by QKS).
// V stored (bh, n/32, d, n%32): per kv-block a contiguous 2KB [32d][32kv] tile.
__global__ __launch_bounds__(256) void k_proj3(
    const unsigned short* __restrict__ t_bf, const unsigned short* __restrict__ Wb,
    const float* __restrict__ bq, const float* __restrict__ bk, const float* __restrict__ bv,
    unsigned short* __restrict__ Qb, unsigned short* __restrict__ Kb,
    unsigned short* __restrict__ Vt)
{
    const int mat  = blockIdx.y;
    const int widx = threadIdx.x >> 6;
    const int lane = threadIdx.x & 63;
    const int g = lane >> 4, l15 = lane & 15;
    const int row0 = blockIdx.x * 64 + widx * 16;
    const int gt_row = row0 + l15;
    const unsigned short* Wm = Wb + mat * 16384;
    const float* bias = (mat == 0) ? bq : (mat == 1) ? bk : bv;

    bf16x8 tf[4];
    #pragma unroll
    for (int kc = 0; kc < 4; ++kc)
        tf[kc] = *(const bf16x8*)(t_bf + (size_t)gt_row * 128 + kc * 32 + g * 8);

    #pragma unroll
    for (int ot = 0; ot < 8; ++ot) {
        f32x4 acc;
        if (mat < 2) {
            float bb = bias[ot * 16 + l15];
            if (mat == 0) bb *= QKS;
            acc[0] = bb; acc[1] = bb; acc[2] = bb; acc[3] = bb;
        } else {
            #pragma unroll
            for (int r = 0; r < 4; ++r) acc[r] = bias[ot * 16 + 4 * g + r];
        }
        #pragma unroll
        for (int kc = 0; kc < 4; ++kc) {
            bf16x8 wf = *(const bf16x8*)(Wm + (size_t)(ot * 16 + l15) * 128 + kc * 32 + g * 8);
            acc = (mat == 2) ? mfma16(wf, tf[kc], acc) : mfma16(tf[kc], wf, acc);
        }
        if (mat < 2) {
            unsigned short* dst = (mat == 0) ? Qb : Kb;
            const int o = ot * 16 + l15, h = o >> 5, d = o & 31;
            #pragma unroll
            for (int r = 0; r < 4; ++r) {
                const int gt = row0 + 4 * g + r;
                const int b = gt >> 12, n = gt & 4095;
                dst[(((size_t)(b * 4 + h)) * 4096 + n) * 32 + d] = f2bf(acc[r]);
            }
        } else {
            const int b = gt_row >> 12, n = gt_row & 4095;
            #pragma unroll
            for (int r = 0; r < 4; ++r) {
                const int o = ot * 16 + 4 * g + r, h = o >> 5, d = o & 31;
                Vt[((size_t)(b * 4 + h) * 128 + (n >> 5)) * 1024 + d * 32 + (n & 31)]
                    = f2bf(acc[r]);
            }
        }
    }
}

// ---------------------------------------------------------------------------
// attn: flash attention, split-KV, MAX-FREE. Block = 4 waves = 2 q-tiles x 2 halves.
// Wave (qt, half): 32 q rows, KV in [half*2048, half*2048+2048), KVBLK=32.
// Swapped QK^T: mfma(K,Q) -> lane(g,l15) reg r = S[q=l15][kv0(+16)+4g+r], where
// S is already logit*log2e (QKS folded into Wq) -> p = exp2(S) directly.
// P packed in-register into PV A-frag with slot map pi(g,j)=16*(j>>2)+4g+(j&3);
// V B-frag uses the identical map -> permutation cancels inside MFMA.
// Denominator = extra PV MFMA against constant-1.0 B operand (acc2*).
// Halves merged through LDS by plain addition (no max state), half 0 writes.
__global__ __launch_bounds__(256) void k_attn(
    const unsigned short* __restrict__ Qb, const unsigned short* __restrict__ Kb,
    const unsigned short* __restrict__ Vt, unsigned short* __restrict__ Ob)
{
    const int widx = threadIdx.x >> 6;
    const int qt   = widx >> 1;          // q-tile within block (0,1)
    const int half = widx & 1;           // KV half (0,1)
    const int qtg  = blockIdx.x * 2 + qt;
    const int bh = qtg >> 7, q0 = (qtg & 127) * 32;
    const int lane = threadIdx.x & 63, g = lane >> 4, l15 = lane & 15;

    __shared__ float lacc[2][32][36];   // [qt][col d][row q], padded
    __shared__ float lden[2][32];       // [qt][row q] denominator (half 1)

    const bf16x8 qf0 = *(const bf16x8*)(Qb + ((size_t)bh * 4096 + q0 + l15) * 32 + g * 8);
    const bf16x8 qf1 = *(const bf16x8*)(Qb + ((size_t)bh * 4096 + q0 + 16 + l15) * 32 + g * 8);

    // K pointer: row (half*2048 + l15), element g*8.  advance 32 rows/step.
    const unsigned short* kp = Kb + (size_t)bh * 131072
                             + (size_t)(half * 2048 + l15) * 32 + g * 8;
    // V pointer: block (half*64), within-tile offset d=l15 row, kv slot 4g.
    const unsigned short* vp = Vt + (size_t)bh * 131072 + (size_t)half * 65536
                             + l15 * 32 + 4 * g;

    bf16x8 onesf;
    #pragma unroll
    for (int j = 0; j < 8; ++j) onesf[j] = (short)0x3F80;  // bf16 1.0

    f32x4 acc00 = {0.f,0.f,0.f,0.f}, acc01 = {0.f,0.f,0.f,0.f};
    f32x4 acc10 = {0.f,0.f,0.f,0.f}, acc11 = {0.f,0.f,0.f,0.f};
    f32x4 acc20 = {0.f,0.f,0.f,0.f}, acc21 = {0.f,0.f,0.f,0.f};
    const f32x4 z = {0.f,0.f,0.f,0.f};

    for (int it = 0; it < 64; ++it) {
        const bf16x8 kf0 = *(const bf16x8*)(kp);
        const bf16x8 kf1 = *(const bf16x8*)(kp + 512);   // rows +16
        const s16x4  v00 = *(const s16x4*)(vp);          // d=l15,  kv 4g+0..3
        const s16x4  v01 = *(const s16x4*)(vp + 16);     // d=l15,  kv 16+4g
        const s16x4  v10 = *(const s16x4*)(vp + 512);    // d=16+l15, kv 4g
        const s16x4  v11 = *(const s16x4*)(vp + 528);    // d=16+l15, kv 16+4g
        kp += 1024;  // 32 kv rows
        vp += 1024;  // next 2KB kv-block tile

        f32x4 s00 = mfma16(kf0, qf0, z), s01 = mfma16(kf1, qf0, z);
        union { bf16x8 v; unsigned int w[4]; } pa0, pa1;
        {
            float p[8];
            #pragma unroll
            for (int i = 0; i < 4; ++i) {
                p[i]     = __builtin_amdgcn_exp2f(s00[i]);
                p[4 + i] = __builtin_amdgcn_exp2f(s01[i]);
            }
            pa0.w[0] = cvt_pk_bf16(p[0], p[1]); pa0.w[1] = cvt_pk_bf16(p[2], p[3]);
            pa0.w[2] = cvt_pk_bf16(p[4], p[5]); pa0.w[3] = cvt_pk_bf16(p[6], p[7]);
        }
        f32x4 s10 = mfma16(kf0, qf1, z), s11 = mfma16(kf1, qf1, z);
        {
            float p[8];
            #pragma unroll
            for (int i = 0; i < 4; ++i) {
                p[i]     = __builtin_amdgcn_exp2f(s10[i]);
                p[4 + i] = __builtin_amdgcn_exp2f(s11[i]);
            }
            pa1.w[0] = cvt_pk_bf16(p[0], p[1]); pa1.w[1] = cvt_pk_bf16(p[2], p[3]);
            pa1.w[2] = cvt_pk_bf16(p[4], p[5]); pa1.w[3] = cvt_pk_bf16(p[6], p[7]);
        }

        union { bf16x8 v; s16x4 h[2]; } vf0, vf1;
        vf0.h[0] = v00; vf0.h[1] = v01;
        vf1.h[0] = v10; vf1.h[1] = v11;

        acc00 = mfma16(pa0.v, vf0.v, acc00);   // rows q0..+15,  O cols 0..15
        acc01 = mfma16(pa0.v, vf1.v, acc01);   //                O cols 16..31
        acc20 = mfma16(pa0.v, onesf, acc20);   // denominator rows q0..+15
        acc10 = mfma16(pa1.v, vf0.v, acc10);   // rows q0+16..+31
        acc11 = mfma16(pa1.v, vf1.v, acc11);
        acc21 = mfma16(pa1.v, onesf, acc21);
    }

    // ---- merge the two KV halves (plain addition; no max state) ------------
    if (half == 1) {
        *(f32x4*)&lacc[qt][l15][4 * g]           = acc00;  // [col][row]
        *(f32x4*)&lacc[qt][16 + l15][4 * g]      = acc01;
        *(f32x4*)&lacc[qt][l15][16 + 4 * g]      = acc10;
        *(f32x4*)&lacc[qt][16 + l15][16 + 4 * g] = acc11;
        if (l15 == 0) {
            #pragma unroll
            for (int r = 0; r < 4; ++r) {
                lden[qt][4 * g + r]      = acc20[r];
                lden[qt][16 + 4 * g + r] = acc21[r];
            }
        }
    }
    __syncthreads();
    if (half == 1) return;

    const int b = bh >> 2, h = bh & 3;
    #pragma unroll
    for (int r = 0; r < 4; ++r) {
        const int row0 = 4 * g + r, row1 = 16 + 4 * g + r;
        const float rd0 = 1.0f / (acc20[r] + lden[qt][row0]);
        const float rd1 = 1.0f / (acc21[r] + lden[qt][row1]);
        const float o00 = acc00[r] + lacc[qt][l15][row0];
        const float o01 = acc01[r] + lacc[qt][16 + l15][row0];
        const float o10 = acc10[r] + lacc[qt][l15][row1];
        const float o11 = acc11[r] + lacc[qt][16 + l15][row1];
        const size_t base0 = ((size_t)b * 4096 + q0 + row0) * 128 + h * 32;
        const size_t base1 = ((size_t)b * 4096 + q0 + row1) * 128 + h * 32;
        Ob[base0 + l15]      = f2bf(o00 * rd0);
        Ob[base0 + 16 + l15] = f2bf(o01 * rd0);
        Ob[base1 + l15]      = f2bf(o10 * rd1);
        Ob[base1 + 16 + l15] = f2bf(o11 * rd1);
    }
}

// ---------------------------------------------------------------------------
// projo: out(b,c,n) = (O @ Wo^T + bo)^T via swapped MFMA (A=Wo rows, B=O rows)
__global__ __launch_bounds__(256) void k_projo(
    const unsigned short* __restrict__ Ob, const unsigned short* __restrict__ Wob,
    const float* __restrict__ bo, float* __restrict__ out)
{
    const int widx = threadIdx.x >> 6;
    const int lane = threadIdx.x & 63, g = lane >> 4, l15 = lane & 15;
    const int gt = blockIdx.x * 64 + widx * 16 + l15;  // token (col of D)
    const int b = gt >> 12, n = gt & 4095;

    bf16x8 of[4];
    #pragma unroll
    for (int kc = 0; kc < 4; ++kc)
        of[kc] = *(const bf16x8*)(Ob + (size_t)gt * 128 + kc * 32 + g * 8);

    #pragma unroll
    for (int ot = 0; ot < 8; ++ot) {
        f32x4 acc;
        #pragma unroll
        for (int r = 0; r < 4; ++r) acc[r] = bo[ot * 16 + 4 * g + r];
        #pragma unroll
        for (int kc = 0; kc < 4; ++kc) {
            bf16x8 wf = *(const bf16x8*)(Wob + (size_t)(ot * 16 + l15) * 128 + kc * 32 + g * 8);
            acc = mfma16(wf, of[kc], acc);
        }
        #pragma unroll
        for (int r = 0; r < 4; ++r)
            out[((size_t)b * 128 + ot * 16 + 4 * g + r) * 4096 + n] = acc[r];
    }
}

// ---------------------------------------------------------------------------
extern "C" void kernel_launch(void* const* d_in, const int* in_sizes, int n_in,
                              void* d_out, int out_size, void* d_ws, size_t ws_size,
                              hipStream_t stream)
{
    const float* x  = (const float*)d_in[0];
    const float* Wq = (const float*)d_in[1];
    const float* bq = (const float*)d_in[2];
    const float* Wk = (const float*)d_in[3];
    const float* bk = (const float*)d_in[4];
    const float* Wv = (const float*)d_in[5];
    const float* bv = (const float*)d_in[6];
    const float* Wo = (const float*)d_in[7];
    const float* bo = (const float*)d_in[8];
    float* out = (float*)d_out;

    char* ws = (char*)d_ws;
    unsigned short* t_bf = (unsigned short*)(ws);             //  8,388,608 B
    unsigned short* Wb   = (unsigned short*)(ws +  8388608);  //    131,072 B
    unsigned short* Qb   = (unsigned short*)(ws +  8519680);  //  8,388,608 B
    unsigned short* Kb   = (unsigned short*)(ws + 16908288);  //  8,388,608 B
    unsigned short* Vt   = (unsigned short*)(ws + 25296896);  //  8,388,608 B
    unsigned short* Ob   = (unsigned short*)(ws + 33685504);  //  8,388,608 B -> 42.1 MB total

    k_prep <<<dim3(1028),     dim3(256), 0, stream>>>(x, Wq, Wk, Wv, Wo, t_bf, Wb);
    k_proj3<<<dim3(512, 3),   dim3(256), 0, stream>>>(t_bf, Wb, bq, bk, bv, Qb, Kb, Vt);
    k_attn <<<dim3(2048),     dim3(256), 0, stream>>>(Qb, Kb, Vt, Ob);
    k_projo<<<dim3(512),      dim3(256), 0, stream>>>(Ob, Wb + 3 * 16384, bo, out);
}

// Round 5
// 230.487 us; speedup vs baseline: 2.9692x; 1.0134x over previous
//
#include <hip/hip_runtime.h>

// MultiHeadSelfAttention2D: B=8, C=128, H=W=64, N=4096, heads=4, hd=32
// Pipeline: prep (transpose x -> tokens bf16, weights -> bf16; Wq pre-scaled
//                 by 1/sqrt(32)*log2(e) so QK^T lands in the exp2 domain)
//           proj3 (QKV via MFMA; V written in (bh, kvblk, d, kv%32) layout)
//           attn  (flash attention, split-KV, MAX-FREE softmax, 2-deep
//                  register double-buffer K/V prefetch)
//           projo (output projection, transposed store)

using f32x4  = __attribute__((ext_vector_type(4))) float;
using bf16x8 = __attribute__((ext_vector_type(8))) short;  // 8 bf16 in 4 VGPRs
using s16x4  = __attribute__((ext_vector_type(4))) short;

#define QSCALE 0.17677669529663687f  // 1/sqrt(32)
#define LOG2E  1.4426950408889634f
#define QKS    (QSCALE * LOG2E)      // folded into Wq/bq -> S = logit*log2e

static __device__ __forceinline__ unsigned short f2bf(float f) {
    union { float f; unsigned int u; } v; v.f = f;
    unsigned int r = v.u + 0x7FFFu + ((v.u >> 16) & 1u);  // RNE
    return (unsigned short)(r >> 16);
}

static __device__ __forceinline__ f32x4 mfma16(bf16x8 a, bf16x8 b, f32x4 c) {
    return __builtin_amdgcn_mfma_f32_16x16x32_bf16(a, b, c, 0, 0, 0);
}

// pack two f32 -> one u32 of two bf16 (lo=a, hi=b); no builtin on gfx950
static __device__ __forceinline__ unsigned int cvt_pk_bf16(float a, float b) {
    unsigned int r;
    asm("v_cvt_pk_bf16_f32 %0, %1, %2" : "=v"(r) : "v"(a), "v"(b));
    return r;
}

// ---------------------------------------------------------------------------
// prep: x (B,128,4096) f32 -> t_bf (B,4096,128) bf16 ; weights f32 -> bf16
__global__ __launch_bounds__(256) void k_prep(
    const float* __restrict__ x,
    const float* __restrict__ Wq, const float* __restrict__ Wk,
    const float* __restrict__ Wv, const float* __restrict__ Wo,
    unsigned short* __restrict__ t_bf, unsigned short* __restrict__ Wb)
{
    const int bx = blockIdx.x;
    const int tid = threadIdx.x;
    if (bx >= 1024) {
        const int m = bx - 1024;
        const float* W = (m == 0) ? Wq : (m == 1) ? Wk : (m == 2) ? Wv : Wo;
        const float s = (m == 0) ? QKS : 1.0f;
        for (int idx = tid; idx < 16384; idx += 256)
            Wb[m * 16384 + idx] = f2bf(W[idx] * s);
        return;
    }
    __shared__ float tl[64][65];  // +1 pad: conflict-free transpose
    const int b  = bx >> 7;
    const int c0 = ((bx >> 6) & 1) * 64;
    const int n0 = (bx & 63) * 64;
    for (int idx = tid; idx < 4096; idx += 256) {
        const int ci = idx >> 6, nj = idx & 63;
        tl[ci][nj] = x[((size_t)(b * 128 + c0 + ci)) * 4096 + n0 + nj];
    }
    __syncthreads();
    for (int idx = tid; idx < 4096; idx += 256) {
        const int nj = idx >> 6, ci = idx & 63;
        t_bf[((size_t)(b * 4096 + n0 + nj)) * 128 + c0 + ci] = f2bf(tl[ci][nj]);
    }
}

// ---------------------------------------------------------------------------
// proj3: Q/K/V = t @ W^T + b.   grid (512, 3): 64 tokens/block, blockIdx.y=mat.
// Q,K stored (bh, n, 32) bf16 (Q pre-scaled by QKS).
// V stored (bh, n/32, d, n%32): per kv-block a contiguous 2KB [32d][32kv] tile.
__global__ __launch_bounds__(256) void k_proj3(
    const unsigned short* __restrict__ t_bf, const unsigned short* __restrict__ Wb,
    const float* __restrict__ bq, const float* __restrict__ bk, const float* __restrict__ bv,
    unsigned short* __restrict__ Qb, unsigned short* __restrict__ Kb,
    unsigned short* __restrict__ Vt)
{
    const int mat  = blockIdx.y;
    const int widx = threadIdx.x >> 6;
    const int lane = threadIdx.x & 63;
    const int g = lane >> 4, l15 = lane & 15;
    const int row0 = blockIdx.x * 64 + widx * 16;
    const int gt_row = row0 + l15;
    const unsigned short* Wm = Wb + mat * 16384;
    const float* bias = (mat == 0) ? bq : (mat == 1) ? bk : bv;

    bf16x8 tf[4];
    #pragma unroll
    for (int kc = 0; kc < 4; ++kc)
        tf[kc] = *(const bf16x8*)(t_bf + (size_t)gt_row * 128 + kc * 32 + g * 8);

    #pragma unroll
    for (int ot = 0; ot < 8; ++ot) {
        f32x4 acc;
        if (mat < 2) {
            float bb = bias[ot * 16 + l15];
            if (mat == 0) bb *= QKS;
            acc[0] = bb; acc[1] = bb; acc[2] = bb; acc[3] = bb;
        } else {
            #pragma unroll
            for (int r = 0; r < 4; ++r) acc[r] = bias[ot * 16 + 4 * g + r];
        }
        #pragma unroll
        for (int kc = 0; kc < 4; ++kc) {
            bf16x8 wf = *(const bf16x8*)(Wm + (size_t)(ot * 16 + l15) * 128 + kc * 32 + g * 8);
            acc = (mat == 2) ? mfma16(wf, tf[kc], acc) : mfma16(tf[kc], wf, acc);
        }
        if (mat < 2) {
            unsigned short* dst = (mat == 0) ? Qb : Kb;
            const int o = ot * 16 + l15, h = o >> 5, d = o & 31;
            #pragma unroll
            for (int r = 0; r < 4; ++r) {
                const int gt = row0 + 4 * g + r;
                const int b = gt >> 12, n = gt & 4095;
                dst[(((size_t)(b * 4 + h)) * 4096 + n) * 32 + d] = f2bf(acc[r]);
            }
        } else {
            const int b = gt_row >> 12, n = gt_row & 4095;
            #pragma unroll
            for (int r = 0; r < 4; ++r) {
                const int o = ot * 16 + 4 * g + r, h = o >> 5, d = o & 31;
                Vt[((size_t)(b * 4 + h) * 128 + (n >> 5)) * 1024 + d * 32 + (n & 31)]
                    = f2bf(acc[r]);
            }
        }
    }
}

// ---------------------------------------------------------------------------
// attn: flash attention, split-KV, MAX-FREE. Block = 4 waves = 2 q-tiles x 2 halves.
// Wave (qt, half): 32 q rows, KV in [half*2048, half*2048+2048), KVBLK=32.
// Swapped QK^T: mfma(K,Q) -> lane(g,l15) reg r = S[q=l15][kv0(+16)+4g+r], where
// S is already logit*log2e (QKS folded into Wq) -> p = exp2(S) directly.
// P packed in-register into PV A-frag with slot map pi(g,j)=16*(j>>2)+4g+(j&3);
// V B-frag uses the identical map -> permutation cancels inside MFMA.
// Denominator = extra PV MFMA against constant-1.0 B operand (acc2*).
// 2-deep register double-buffer: loads for tile t+1 issued before computing t.
// Halves merged through LDS by plain addition (no max state), half 0 writes.
__global__ __launch_bounds__(256) void k_attn(
    const unsigned short* __restrict__ Qb, const unsigned short* __restrict__ Kb,
    const unsigned short* __restrict__ Vt, unsigned short* __restrict__ Ob)
{
    const int widx = threadIdx.x >> 6;
    const int qt   = widx >> 1;          // q-tile within block (0,1)
    const int half = widx & 1;           // KV half (0,1)
    const int qtg  = blockIdx.x * 2 + qt;
    const int bh = qtg >> 7, q0 = (qtg & 127) * 32;
    const int lane = threadIdx.x & 63, g = lane >> 4, l15 = lane & 15;

    __shared__ float lacc[2][32][36];   // [qt][col d][row q], padded
    __shared__ float lden[2][32];       // [qt][row q] denominator (half 1)

    const bf16x8 qf0 = *(const bf16x8*)(Qb + ((size_t)bh * 4096 + q0 + l15) * 32 + g * 8);
    const bf16x8 qf1 = *(const bf16x8*)(Qb + ((size_t)bh * 4096 + q0 + 16 + l15) * 32 + g * 8);

    // K pointer: row (half*2048 + l15), element g*8.  advance 32 rows/step.
    const unsigned short* kp = Kb + (size_t)bh * 131072
                             + (size_t)(half * 2048 + l15) * 32 + g * 8;
    // V pointer: block (half*64), within-tile offset d=l15 row, kv slot 4g.
    const unsigned short* vp = Vt + (size_t)bh * 131072 + (size_t)half * 65536
                             + l15 * 32 + 4 * g;

    bf16x8 onesf;
    #pragma unroll
    for (int j = 0; j < 8; ++j) onesf[j] = (short)0x3F80;  // bf16 1.0

    f32x4 acc00 = {0.f,0.f,0.f,0.f}, acc01 = {0.f,0.f,0.f,0.f};
    f32x4 acc10 = {0.f,0.f,0.f,0.f}, acc11 = {0.f,0.f,0.f,0.f};
    f32x4 acc20 = {0.f,0.f,0.f,0.f}, acc21 = {0.f,0.f,0.f,0.f};
    const f32x4 z = {0.f,0.f,0.f,0.f};

#define LOAD_KV(OFS, KF0, KF1, V00, V01, V10, V11)                             \
    {                                                                          \
      KF0 = *(const bf16x8*)(kp + (OFS));                                      \
      KF1 = *(const bf16x8*)(kp + (OFS) + 512);                                \
      V00 = *(const s16x4*)(vp + (OFS));                                       \
      V01 = *(const s16x4*)(vp + (OFS) + 16);                                  \
      V10 = *(const s16x4*)(vp + (OFS) + 512);                                 \
      V11 = *(const s16x4*)(vp + (OFS) + 528);                                 \
    }

#define ATTN_STEP(KF0, KF1, V00, V01, V10, V11)                                \
    {                                                                          \
      f32x4 s00 = mfma16(KF0, qf0, z), s01 = mfma16(KF1, qf0, z);              \
      f32x4 s10 = mfma16(KF0, qf1, z), s11 = mfma16(KF1, qf1, z);              \
      union { bf16x8 v; unsigned int w[4]; } pa0, pa1;                         \
      {                                                                        \
        float p[8];                                                            \
        _Pragma("unroll")                                                      \
        for (int i = 0; i < 4; ++i) {                                          \
            p[i]     = __builtin_amdgcn_exp2f(s00[i]);                         \
            p[4 + i] = __builtin_amdgcn_exp2f(s01[i]);                         \
        }                                                                      \
        pa0.w[0] = cvt_pk_bf16(p[0], p[1]); pa0.w[1] = cvt_pk_bf16(p[2], p[3]);\
        pa0.w[2] = cvt_pk_bf16(p[4], p[5]); pa0.w[3] = cvt_pk_bf16(p[6], p[7]);\
      }                                                                        \
      {                                                                        \
        float p[8];                                                            \
        _Pragma("unroll")                                                      \
        for (int i = 0; i < 4; ++i) {                                          \
            p[i]     = __builtin_amdgcn_exp2f(s10[i]);                         \
            p[4 + i] = __builtin_amdgcn_exp2f(s11[i]);                         \
        }                                                                      \
        pa1.w[0] = cvt_pk_bf16(p[0], p[1]); pa1.w[1] = cvt_pk_bf16(p[2], p[3]);\
        pa1.w[2] = cvt_pk_bf16(p[4], p[5]); pa1.w[3] = cvt_pk_bf16(p[6], p[7]);\
      }                                                                        \
      union { bf16x8 v; s16x4 h[2]; } vf0, vf1;                                \
      vf0.h[0] = V00; vf0.h[1] = V01;                                          \
      vf1.h[0] = V10; vf1.h[1] = V11;                                          \
      acc00 = mfma16(pa0.v, vf0.v, acc00);                                     \
      acc01 = mfma16(pa0.v, vf1.v, acc01);                                     \
      acc20 = mfma16(pa0.v, onesf, acc20);                                     \
      acc10 = mfma16(pa1.v, vf0.v, acc10);                                     \
      acc11 = mfma16(pa1.v, vf1.v, acc11);                                     \
      acc21 = mfma16(pa1.v, onesf, acc21);                                     \
    }

    bf16x8 kA0, kA1, kB0, kB1;
    s16x4 vA00, vA01, vA10, vA11, vB00, vB01, vB10, vB11;

    LOAD_KV(0, kA0, kA1, vA00, vA01, vA10, vA11);          // tile 0
    for (int it = 0; it < 64; it += 2) {
        LOAD_KV(1024, kB0, kB1, vB00, vB01, vB10, vB11);   // tile t+1
        ATTN_STEP(kA0, kA1, vA00, vA01, vA10, vA11);       // compute tile t
        LOAD_KV(2048, kA0, kA1, vA00, vA01, vA10, vA11);   // tile t+2 (last: dead,
                                                           //  <=4KB past region, valid ws)
        ATTN_STEP(kB0, kB1, vB00, vB01, vB10, vB11);       // compute tile t+1
        kp += 2048;
        vp += 2048;
    }
#undef LOAD_KV
#undef ATTN_STEP

    // ---- merge the two KV halves (plain addition; no max state) ------------
    if (half == 1) {
        *(f32x4*)&lacc[qt][l15][4 * g]           = acc00;  // [col][row]
        *(f32x4*)&lacc[qt][16 + l15][4 * g]      = acc01;
        *(f32x4*)&lacc[qt][l15][16 + 4 * g]      = acc10;
        *(f32x4*)&lacc[qt][16 + l15][16 + 4 * g] = acc11;
        if (l15 == 0) {
            #pragma unroll
            for (int r = 0; r < 4; ++r) {
                lden[qt][4 * g + r]      = acc20[r];
                lden[qt][16 + 4 * g + r] = acc21[r];
            }
        }
    }
    __syncthreads();
    if (half == 1) return;

    const int b = bh >> 2, h = bh & 3;
    #pragma unroll
    for (int r = 0; r < 4; ++r) {
        const int row0 = 4 * g + r, row1 = 16 + 4 * g + r;
        const float rd0 = 1.0f / (acc20[r] + lden[qt][row0]);
        const float rd1 = 1.0f / (acc21[r] + lden[qt][row1]);
        const float o00 = acc00[r] + lacc[qt][l15][row0];
        const float o01 = acc01[r] + lacc[qt][16 + l15][row0];
        const float o10 = acc10[r] + lacc[qt][l15][row1];
        const float o11 = acc11[r] + lacc[qt][16 + l15][row1];
        const size_t base0 = ((size_t)b * 4096 + q0 + row0) * 128 + h * 32;
        const size_t base1 = ((size_t)b * 4096 + q0 + row1) * 128 + h * 32;
        Ob[base0 + l15]      = f2bf(o00 * rd0);
        Ob[base0 + 16 + l15] = f2bf(o01 * rd0);
        Ob[base1 + l15]      = f2bf(o10 * rd1);
        Ob[base1 + 16 + l15] = f2bf(o11 * rd1);
    }
}

// ---------------------------------------------------------------------------
// projo: out(b,c,n) = (O @ Wo^T + bo)^T via swapped MFMA (A=Wo rows, B=O rows)
__global__ __launch_bounds__(256) void k_projo(
    const unsigned short* __restrict__ Ob, const unsigned short* __restrict__ Wob,
    const float* __restrict__ bo, float* __restrict__ out)
{
    const int widx = threadIdx.x >> 6;
    const int lane = threadIdx.x & 63, g = lane >> 4, l15 = lane & 15;
    const int gt = blockIdx.x * 64 + widx * 16 + l15;  // token (col of D)
    const int b = gt >> 12, n = gt & 4095;

    bf16x8 of[4];
    #pragma unroll
    for (int kc = 0; kc < 4; ++kc)
        of[kc] = *(const bf16x8*)(Ob + (size_t)gt * 128 + kc * 32 + g * 8);

    #pragma unroll
    for (int ot = 0; ot < 8; ++ot) {
        f32x4 acc;
        #pragma unroll
        for (int r = 0; r < 4; ++r) acc[r] = bo[ot * 16 + 4 * g + r];
        #pragma unroll
        for (int kc = 0; kc < 4; ++kc) {
            bf16x8 wf = *(const bf16x8*)(Wob + (size_t)(ot * 16 + l15) * 128 + kc * 32 + g * 8);
            acc = mfma16(wf, of[kc], acc);
        }
        #pragma unroll
        for (int r = 0; r < 4; ++r)
            out[((size_t)b * 128 + ot * 16 + 4 * g + r) * 4096 + n] = acc[r];
    }
}

// ---------------------------------------------------------------------------
extern "C" void kernel_launch(void* const* d_in, const int* in_sizes, int n_in,
                              void* d_out, int out_size, void* d_ws, size_t ws_size,
                              hipStream_t stream)
{
    const float* x  = (const float*)d_in[0];
    const float* Wq = (const float*)d_in[1];
    const float* bq = (const float*)d_in[2];
    const float* Wk = (const float*)d_in[3];
    const float* bk = (const float*)d_in[4];
    const float* Wv = (const float*)d_in[5];
    const float* bv = (const float*)d_in[6];
    const float* Wo = (const float*)d_in[7];
    const float* bo = (const float*)d_in[8];
    float* out = (float*)d_out;

    char* ws = (char*)d_ws;
    unsigned short* t_bf = (unsigned short*)(ws);             //  8,388,608 B
    unsigned short* Wb   = (unsigned short*)(ws +  8388608);  //    131,072 B
    unsigned short* Qb   = (unsigned short*)(ws +  8519680);  //  8,388,608 B
    unsigned short* Kb   = (unsigned short*)(ws + 16908288);  //  8,388,608 B
    unsigned short* Vt   = (unsigned short*)(ws + 25296896);  //  8,388,608 B
    unsigned short* Ob   = (unsigned short*)(ws + 33685504);  //  8,388,608 B -> 42.1 MB total

    k_prep <<<dim3(1028),     dim3(256), 0, stream>>>(x, Wq, Wk, Wv, Wo, t_bf, Wb);
    k_proj3<<<dim3(512, 3),   dim3(256), 0, stream>>>(t_bf, Wb, bq, bk, bv, Qb, Kb, Vt);
    k_attn <<<dim3(2048),     dim3(256), 0, stream>>>(Qb, Kb, Vt, Ob);
    k_projo<<<dim3(512),      dim3(256), 0, stream>>>(Ob, Wb + 3 * 16384, bo, out);
}

// Round 8
// 177.945 us; speedup vs baseline: 3.8460x; 1.2953x over previous
//
#include <hip/hip_runtime.h>

// MultiHeadSelfAttention2D: B=8, C=128, H=W=64, N=4096, heads=4, hd=32
// Pipeline: prep (transpose x -> tokens bf16, weights -> bf16; Wq pre-scaled
//                 by 1/sqrt(32)*log2(e) so QK^T lands in the exp2 domain)
//           proj3 (QKV via MFMA; V written PRE-FRAGMENTED per kv-block so the
//                  attn B-operand is a single 16B load per lane)
//           attn  (flash attention, 4-way split-KV, MAX-FREE softmax,
//                  2-deep register prefetch, XCD-swizzled blocks, LDS merge)
//           projo (output projection, transposed store)

using f32x4  = __attribute__((ext_vector_type(4))) float;
using bf16x8 = __attribute__((ext_vector_type(8))) short;  // 8 bf16 in 4 VGPRs
using s16x4  = __attribute__((ext_vector_type(4))) short;

#define QSCALE 0.17677669529663687f  // 1/sqrt(32)
#define LOG2E  1.4426950408889634f
#define QKS    (QSCALE * LOG2E)      // folded into Wq/bq -> S = logit*log2e

static __device__ __forceinline__ unsigned short f2bf(float f) {
    union { float f; unsigned int u; } v; v.f = f;
    unsigned int r = v.u + 0x7FFFu + ((v.u >> 16) & 1u);  // RNE
    return (unsigned short)(r >> 16);
}

static __device__ __forceinline__ f32x4 mfma16(bf16x8 a, bf16x8 b, f32x4 c) {
    return __builtin_amdgcn_mfma_f32_16x16x32_bf16(a, b, c, 0, 0, 0);
}

// pack two f32 -> one u32 of two bf16 (lo=a, hi=b); no builtin on gfx950
static __device__ __forceinline__ unsigned int cvt_pk_bf16(float a, float b) {
    unsigned int r;
    asm("v_cvt_pk_bf16_f32 %0, %1, %2" : "=v"(r) : "v"(a), "v"(b));
    return r;
}

// ---------------------------------------------------------------------------
// prep: x (B,128,4096) f32 -> t_bf (B,4096,128) bf16 ; weights f32 -> bf16
__global__ __launch_bounds__(256) void k_prep(
    const float* __restrict__ x,
    const float* __restrict__ Wq, const float* __restrict__ Wk,
    const float* __restrict__ Wv, const float* __restrict__ Wo,
    unsigned short* __restrict__ t_bf, unsigned short* __restrict__ Wb)
{
    const int bx = blockIdx.x;
    const int tid = threadIdx.x;
    if (bx >= 1024) {
        const int m = bx - 1024;
        const float* W = (m == 0) ? Wq : (m == 1) ? Wk : (m == 2) ? Wv : Wo;
        const float s = (m == 0) ? QKS : 1.0f;
        for (int idx = tid; idx < 16384; idx += 256)
            Wb[m * 16384 + idx] = f2bf(W[idx] * s);
        return;
    }
    __shared__ float tl[64][65];  // +1 pad: conflict-free transpose
    const int b  = bx >> 7;
    const int c0 = ((bx >> 6) & 1) * 64;
    const int n0 = (bx & 63) * 64;
    for (int idx = tid; idx < 4096; idx += 256) {
        const int ci = idx >> 6, nj = idx & 63;
        tl[ci][nj] = x[((size_t)(b * 128 + c0 + ci)) * 4096 + n0 + nj];
    }
    __syncthreads();
    for (int idx = tid; idx < 4096; idx += 256) {
        const int nj = idx >> 6, ci = idx & 63;
        t_bf[((size_t)(b * 4096 + n0 + nj)) * 128 + c0 + ci] = f2bf(tl[ci][nj]);
    }
}

// ---------------------------------------------------------------------------
// proj3: Q/K/V = t @ W^T + b.   grid (512, 3): 64 tokens/block, blockIdx.y=mat.
// Q,K stored (bh, n, 32) bf16 (Q pre-scaled by QKS).
// V stored per kv-block as a 2KB tile [32 rows d][32 kv], with each row's kv
// order pre-fragmented: row position 8*g + 4*hi + lo  <->  kv = 16*hi + 4*g + lo.
// Lane (g,l15) of the attn PV B-frag then reads ONE 16B chunk at byte 16*g.
__global__ __launch_bounds__(256) void k_proj3(
    const unsigned short* __restrict__ t_bf, const unsigned short* __restrict__ Wb,
    const float* __restrict__ bq, const float* __restrict__ bk, const float* __restrict__ bv,
    unsigned short* __restrict__ Qb, unsigned short* __restrict__ Kb,
    unsigned short* __restrict__ Vt)
{
    const int mat  = blockIdx.y;
    const int widx = threadIdx.x >> 6;
    const int lane = threadIdx.x & 63;
    const int g = lane >> 4, l15 = lane & 15;
    const int row0 = blockIdx.x * 64 + widx * 16;
    const int gt_row = row0 + l15;
    const unsigned short* Wm = Wb + mat * 16384;
    const float* bias = (mat == 0) ? bq : (mat == 1) ? bk : bv;

    bf16x8 tf[4];
    #pragma unroll
    for (int kc = 0; kc < 4; ++kc)
        tf[kc] = *(const bf16x8*)(t_bf + (size_t)gt_row * 128 + kc * 32 + g * 8);

    #pragma unroll
    for (int ot = 0; ot < 8; ++ot) {
        f32x4 acc;
        if (mat < 2) {
            float bb = bias[ot * 16 + l15];
            if (mat == 0) bb *= QKS;
            acc[0] = bb; acc[1] = bb; acc[2] = bb; acc[3] = bb;
        } else {
            #pragma unroll
            for (int r = 0; r < 4; ++r) acc[r] = bias[ot * 16 + 4 * g + r];
        }
        #pragma unroll
        for (int kc = 0; kc < 4; ++kc) {
            bf16x8 wf = *(const bf16x8*)(Wm + (size_t)(ot * 16 + l15) * 128 + kc * 32 + g * 8);
            acc = (mat == 2) ? mfma16(wf, tf[kc], acc) : mfma16(tf[kc], wf, acc);
        }
        if (mat < 2) {
            unsigned short* dst = (mat == 0) ? Qb : Kb;
            const int o = ot * 16 + l15, h = o >> 5, d = o & 31;
            #pragma unroll
            for (int r = 0; r < 4; ++r) {
                const int gt = row0 + 4 * g + r;
                const int b = gt >> 12, n = gt & 4095;
                dst[(((size_t)(b * 4 + h)) * 4096 + n) * 32 + d] = f2bf(acc[r]);
            }
        } else {
            const int b = gt_row >> 12, n = gt_row & 4095;
            const int n31 = n & 31;
            // pre-fragmented position within the 32-wide row
            const int pos = ((n31 >> 2) & 3) * 8 + ((n31 >> 4) & 1) * 4 + (n31 & 3);
            #pragma unroll
            for (int r = 0; r < 4; ++r) {
                const int o = ot * 16 + 4 * g + r, h2 = o >> 5, d = o & 31;
                const size_t tb2 = ((size_t)(b * 4 + h2) * 128 + ((n >> 5) & 127)) * 1024;
                Vt[tb2 + d * 32 + pos] = f2bf(acc[r]);
            }
        }
    }
}

// ---------------------------------------------------------------------------
// attn: flash attention, 4-way split-KV, MAX-FREE. Block = 4 waves = 1 q-tile
// x 4 KV quarters. Wave widx: 32 q rows, KV in [widx*1024, widx*1024+1024).
// Swapped QK^T: mfma(K,Q) -> lane(g,l15) reg r = S[q=l15][kv0(+16)+4g+r], where
// S is already logit*log2e (QKS folded into Wq) -> p = exp2(S) directly.
// P packed in-register into PV A-frag with slot map pi(g,j)=16*(j>>2)+4g+(j&3);
// V B-frag is ONE 16B load thanks to the pre-fragmented Vt layout (same map).
// Denominator = extra PV MFMA against constant-1.0 B operand (acc2*).
// Quarters merged through LDS by plain addition, wave 0 writes.
// NOTE: no min-waves launch-bounds arg — natural VGPR (~52-60) already allows
// the 8-wave tier; forcing (256,8) in R7 coincided with a numeric failure.
__global__ __launch_bounds__(256) void k_attn(
    const unsigned short* __restrict__ Qb, const unsigned short* __restrict__ Kb,
    const unsigned short* __restrict__ Vt, unsigned short* __restrict__ Ob)
{
    // bijective XCD swizzle (4096 blocks % 8 == 0): XCD x gets a contiguous
    // 512-block chunk -> 4 bh (1 MB K/V) working set per XCD L2.
    const int bid = blockIdx.x;
    const int swz = (bid & 7) * 512 + (bid >> 3);
    const int widx = threadIdx.x >> 6;           // KV quarter 0..3
    const int bh = swz >> 7, q0 = (swz & 127) * 32;
    const int lane = threadIdx.x & 63, g = lane >> 4, l15 = lane & 15;

    __shared__ float lacc[3][32][36];   // [writer][col d][row q], padded
    __shared__ float lden[3][32];       // [writer][row q]

    const bf16x8 qf0 = *(const bf16x8*)(Qb + ((size_t)bh * 4096 + q0 + l15) * 32 + g * 8);
    const bf16x8 qf1 = *(const bf16x8*)(Qb + ((size_t)bh * 4096 + q0 + 16 + l15) * 32 + g * 8);

    // K pointer: row (widx*1024 + l15), element g*8.  +1024 elems per 32-kv tile.
    const unsigned short* kp = Kb + (size_t)bh * 131072
                             + (size_t)(widx * 1024 + l15) * 32 + g * 8;
    // V pointer: quarter base, row d=l15, fragment chunk g (16B).
    const unsigned short* vp = Vt + (size_t)bh * 131072 + (size_t)widx * 32768
                             + l15 * 32 + g * 8;

    bf16x8 onesf;
    #pragma unroll
    for (int j = 0; j < 8; ++j) onesf[j] = (short)0x3F80;  // bf16 1.0

    f32x4 acc00 = {0.f,0.f,0.f,0.f}, acc01 = {0.f,0.f,0.f,0.f};
    f32x4 acc10 = {0.f,0.f,0.f,0.f}, acc11 = {0.f,0.f,0.f,0.f};
    f32x4 acc20 = {0.f,0.f,0.f,0.f}, acc21 = {0.f,0.f,0.f,0.f};
    const f32x4 z = {0.f,0.f,0.f,0.f};

#define LOAD_KV(OFS, KF0, KF1, VF0, VF1)                                       \
    {                                                                          \
      KF0 = *(const bf16x8*)(kp + (OFS));                                      \
      KF1 = *(const bf16x8*)(kp + (OFS) + 512);                                \
      VF0 = *(const bf16x8*)(vp + (OFS));          /* d = l15      */          \
      VF1 = *(const bf16x8*)(vp + (OFS) + 512);    /* d = 16 + l15 */          \
    }

#define ATTN_STEP(KF0, KF1, VF0, VF1)                                          \
    {                                                                          \
      f32x4 s00 = mfma16(KF0, qf0, z), s01 = mfma16(KF1, qf0, z);              \
      f32x4 s10 = mfma16(KF0, qf1, z), s11 = mfma16(KF1, qf1, z);              \
      union { bf16x8 v; unsigned int w[4]; } pa0, pa1;                         \
      {                                                                        \
        float p[8];                                                            \
        _Pragma("unroll")                                                      \
        for (int i = 0; i < 4; ++i) {                                          \
            p[i]     = __builtin_amdgcn_exp2f(s00[i]);                         \
            p[4 + i] = __builtin_amdgcn_exp2f(s01[i]);                         \
        }                                                                      \
        pa0.w[0] = cvt_pk_bf16(p[0], p[1]); pa0.w[1] = cvt_pk_bf16(p[2], p[3]);\
        pa0.w[2] = cvt_pk_bf16(p[4], p[5]); pa0.w[3] = cvt_pk_bf16(p[6], p[7]);\
      }                                                                        \
      {                                                                        \
        float p[8];                                                            \
        _Pragma("unroll")                                                      \
        for (int i = 0; i < 4; ++i) {                                          \
            p[i]     = __builtin_amdgcn_exp2f(s10[i]);                         \
            p[4 + i] = __builtin_amdgcn_exp2f(s11[i]);                         \
        }                                                                      \
        pa1.w[0] = cvt_pk_bf16(p[0], p[1]); pa1.w[1] = cvt_pk_bf16(p[2], p[3]);\
        pa1.w[2] = cvt_pk_bf16(p[4], p[5]); pa1.w[3] = cvt_pk_bf16(p[6], p[7]);\
      }                                                                        \
      acc00 = mfma16(pa0.v, VF0, acc00);                                       \
      acc01 = mfma16(pa0.v, VF1, acc01);                                       \
      acc20 = mfma16(pa0.v, onesf, acc20);                                     \
      acc10 = mfma16(pa1.v, VF0, acc10);                                       \
      acc11 = mfma16(pa1.v, VF1, acc11);                                       \
      acc21 = mfma16(pa1.v, onesf, acc21);                                     \
    }

    bf16x8 kA0, kA1, kB0, kB1, vA0, vA1, vB0, vB1;

    LOAD_KV(0, kA0, kA1, vA0, vA1);                 // tile 0
    for (int it = 0; it < 32; it += 2) {
        LOAD_KV(1024, kB0, kB1, vB0, vB1);          // tile t+1
        ATTN_STEP(kA0, kA1, vA0, vA1);              // compute tile t
        LOAD_KV(2048, kA0, kA1, vA0, vA1);          // tile t+2 (last: dead,
                                                    //  <=4KB past quarter, valid ws)
        ATTN_STEP(kB0, kB1, vB0, vB1);              // compute tile t+1
        kp += 2048;
        vp += 2048;
    }
#undef LOAD_KV
#undef ATTN_STEP

    // ---- merge the four quarters (plain addition; no max state) ------------
    if (widx != 0) {
        const int s = widx - 1;
        *(f32x4*)&lacc[s][l15][4 * g]           = acc00;  // [col][row]
        *(f32x4*)&lacc[s][16 + l15][4 * g]      = acc01;
        *(f32x4*)&lacc[s][l15][16 + 4 * g]      = acc10;
        *(f32x4*)&lacc[s][16 + l15][16 + 4 * g] = acc11;
        if (l15 == 0) {
            #pragma unroll
            for (int r = 0; r < 4; ++r) {
                lden[s][4 * g + r]      = acc20[r];
                lden[s][16 + 4 * g + r] = acc21[r];
            }
        }
    }
    __syncthreads();
    if (widx != 0) return;

    const int b = bh >> 2, h = bh & 3;
    #pragma unroll
    for (int r = 0; r < 4; ++r) {
        const int row0 = 4 * g + r, row1 = 16 + 4 * g + r;
        const float rd0 = 1.0f / (acc20[r] + lden[0][row0] + lden[1][row0] + lden[2][row0]);
        const float rd1 = 1.0f / (acc21[r] + lden[0][row1] + lden[1][row1] + lden[2][row1]);
        const float o00 = acc00[r] + lacc[0][l15][row0]      + lacc[1][l15][row0]      + lacc[2][l15][row0];
        const float o01 = acc01[r] + lacc[0][16 + l15][row0] + lacc[1][16 + l15][row0] + lacc[2][16 + l15][row0];
        const float o10 = acc10[r] + lacc[0][l15][row1]      + lacc[1][l15][row1]      + lacc[2][l15][row1];
        const float o11 = acc11[r] + lacc[0][16 + l15][row1] + lacc[1][16 + l15][row1] + lacc[2][16 + l15][row1];
        const size_t base0 = ((size_t)b * 4096 + q0 + row0) * 128 + h * 32;
        const size_t base1 = ((size_t)b * 4096 + q0 + row1) * 128 + h * 32;
        Ob[base0 + l15]      = f2bf(o00 * rd0);
        Ob[base0 + 16 + l15] = f2bf(o01 * rd0);
        Ob[base1 + l15]      = f2bf(o10 * rd1);
        Ob[base1 + 16 + l15] = f2bf(o11 * rd1);
    }
}

// ---------------------------------------------------------------------------
// projo: out(b,c,n) = (O @ Wo^T + bo)^T via swapped MFMA (A=Wo rows, B=O rows)
__global__ __launch_bounds__(256) void k_projo(
    const unsigned short* __restrict__ Ob, const unsigned short* __restrict__ Wob,
    const float* __restrict__ bo, float* __restrict__ out)
{
    const int widx = threadIdx.x >> 6;
    const int lane = threadIdx.x & 63, g = lane >> 4, l15 = lane & 15;
    const int gt = blockIdx.x * 64 + widx * 16 + l15;  // token (col of D)
    const int b = gt >> 12, n = gt & 4095;

    bf16x8 of[4];
    #pragma unroll
    for (int kc = 0; kc < 4; ++kc)
        of[kc] = *(const bf16x8*)(Ob + (size_t)gt * 128 + kc * 32 + g * 8);

    #pragma unroll
    for (int ot = 0; ot < 8; ++ot) {
        f32x4 acc;
        #pragma unroll
        for (int r = 0; r < 4; ++r) acc[r] = bo[ot * 16 + 4 * g + r];
        #pragma unroll
        for (int kc = 0; kc < 4; ++kc) {
            bf16x8 wf = *(const bf16x8*)(Wob + (size_t)(ot * 16 + l15) * 128 + kc * 32 + g * 8);
            acc = mfma16(wf, of[kc], acc);
        }
        #pragma unroll
        for (int r = 0; r < 4; ++r)
            out[((size_t)b * 128 + ot * 16 + 4 * g + r) * 4096 + n] = acc[r];
    }
}

// ---------------------------------------------------------------------------
extern "C" void kernel_launch(void* const* d_in, const int* in_sizes, int n_in,
                              void* d_out, int out_size, void* d_ws, size_t ws_size,
                              hipStream_t stream)
{
    const float* x  = (const float*)d_in[0];
    const float* Wq = (const float*)d_in[1];
    const float* bq = (const float*)d_in[2];
    const float* Wk = (const float*)d_in[3];
    const float* bk = (const float*)d_in[4];
    const float* Wv = (const float*)d_in[5];
    const float* bv = (const float*)d_in[6];
    const float* Wo = (const float*)d_in[7];
    const float* bo = (const float*)d_in[8];
    float* out = (float*)d_out;

    char* ws = (char*)d_ws;
    unsigned short* t_bf = (unsigned short*)(ws);             //  8,388,608 B
    unsigned short* Wb   = (unsigned short*)(ws +  8388608);  //    131,072 B
    unsigned short* Qb   = (unsigned short*)(ws +  8519680);  //  8,388,608 B
    unsigned short* Kb   = (unsigned short*)(ws + 16908288);  //  8,388,608 B
    unsigned short* Vt   = (unsigned short*)(ws + 25296896);  //  8,388,608 B
    unsigned short* Ob   = (unsigned short*)(ws + 33685504);  //  8,388,608 B -> 42.1 MB total

    k_prep <<<dim3(1028),     dim3(256), 0, stream>>>(x, Wq, Wk, Wv, Wo, t_bf, Wb);
    k_proj3<<<dim3(512, 3),   dim3(256), 0, stream>>>(t_bf, Wb, bq, bk, bv, Qb, Kb, Vt);
    k_attn <<<dim3(4096),     dim3(256), 0, stream>>>(Qb, Kb, Vt, Ob);
    k_projo<<<dim3(512),      dim3(256), 0, stream>>>(Ob, Wb + 3 * 16384, bo, out);
}